// Round 18
// 949.075 us; speedup vs baseline: 1.5129x; 1.0350x over previous
//
#include <hip/hip_runtime.h>
#include <math.h>

typedef float2 cplx;
#define PI_D 3.14159265358979323846

__device__ __forceinline__ int iabs_(int v){ return v < 0 ? -v : v; }

// ======================= table kernels =======================
__global__ void k_tables(double* lf, double* wq){
  if(threadIdx.x == 0){
    lf[0] = 0.0;
    double acc = 0.0;
    for(int i = 1; i <= 128; ++i){ acc += log((double)i); lf[i] = acc; }
  }
  int t = threadIdx.x;
  int b, j, off;
  if(t < 64){ b = 32; j = t; off = 0; }
  else if(t < 96){ b = 16; j = t - 64; off = 64; }
  else if(t < 112){ b = 8; j = t - 96; off = 96; }
  else if(t < 120){ b = 4; j = t - 112; off = 112; }
  else return;
  double beta = PI_D * (2*j+1) / (4.0*b);
  double s = 0.0;
  for(int p = 0; p < b; ++p) s += sin((2*p+1)*beta) / (2*p+1);
  wq[off+j] = 2.0*PI_D/((double)b*b) * sin(beta) * s;
}

__global__ void k_twiddle(cplx* E, int nfreq, int n, int center, double sgn){
  int idx = blockIdx.x*blockDim.x + threadIdx.x;
  if(idx >= nfreq*n) return;
  int p = idx / n, a = idx % n;
  double ang = sgn * 2.0*PI_D * (double)(p-center) * (double)a / (double)n;
  E[idx] = make_float2((float)cos(ang), (float)sin(ang));
}

// Wigner-d, n=0 column only; smode: 0 none, 1 *(2l+1), 2 *wqs[j]
__global__ void k_wigner_col0(const double* __restrict__ lf, float* __restrict__ out,
                              int nb, int Lmax, int W, int mode, int bq,
                              const double* __restrict__ wqs, int smode){
  int idx = blockIdx.x*blockDim.x + threadIdx.x;
  int total = nb*Lmax*W;
  if(idx >= total) return;
  int m = idx % W;
  int l = (idx/W) % Lmax;
  int j = idx/(W*Lmax);
  int cw = (W-1)/2;
  int mh = m - cw;
  float r = 0.f;
  if(iabs_(mh) <= l){
    double beta = (mode==0) ? PI_D*(2*j+1)/(4.0*bq) : PI_D*(j+1)/16.0;
    double cb = cos(0.5*beta), sb = sin(0.5*beta);
    double lcb = log(cb), lsb = log(sb);
    int k0 = (mh < 0) ? -mh : 0;
    int k1 = (mh > 0) ? (l - mh) : l;
    double s = 0.0;
    for(int k = k0; k <= k1; ++k){
      double logc = 0.5*(lf[l+mh] + lf[l-mh] + 2.0*lf[l])
                    - lf[l-k] - lf[k] - lf[mh+k] - lf[l-mh-k];
      double term = exp(logc + (double)(2*l - mh - 2*k)*lcb + (double)(mh + 2*k)*lsb);
      s += ((mh + k) & 1) ? -term : term;
    }
    if(smode == 1) s *= (double)(2*l+1);
    else if(smode == 2) s *= wqs[j];
    r = (float)s;
  }
  out[idx] = r;
}

// Full Wigner-d; smode: 0 none, 1 *(2l+1), 2 *wqs[j]
__global__ void k_wigner_full(const double* __restrict__ lf, float* __restrict__ out,
                              int nb, int L, int W, int mode, int bq,
                              const double* __restrict__ wqs, int smode){
  int idx = blockIdx.x*blockDim.x + threadIdx.x;
  int total = nb*L*W*W;
  if(idx >= total) return;
  int q = idx % W;
  int p = (idx/W) % W;
  int l = (idx/(W*W)) % L;
  int j = idx/(W*W*L);
  int cw = (W-1)/2;
  int mh = p - cw, nh = q - cw;
  float r = 0.f;
  if(iabs_(mh) <= l && iabs_(nh) <= l){
    double beta = (mode==0) ? PI_D*(2*j+1)/(4.0*bq) : PI_D*(j+1)/16.0;
    double cb = cos(0.5*beta), sb = sin(0.5*beta);
    double lcb = log(cb), lsb = log(sb);
    int k0 = (nh - mh > 0) ? (nh - mh) : 0;
    int a1 = l + nh, b1 = l - mh;
    int k1 = (a1 < b1) ? a1 : b1;
    double s = 0.0;
    for(int k = k0; k <= k1; ++k){
      double logc = 0.5*(lf[l+mh] + lf[l-mh] + lf[l+nh] + lf[l-nh])
                    - lf[l+nh-k] - lf[k] - lf[mh-nh+k] - lf[l-mh-k];
      double term = exp(logc + (double)(2*l + nh - mh - 2*k)*lcb + (double)(mh - nh + 2*k)*lsb);
      s += ((mh - nh + k) & 1) ? -term : term;
    }
    if(smode == 1) s *= (double)(2*l+1);
    else if(smode == 2) s *= wqs[j];
    r = (float)s;
  }
  out[idx] = r;
}

// Merged: computes the Wigner series ONCE, writes outA = d*(2l+1), outB = d*wqs[j].
__global__ void k_wigner_full2(const double* __restrict__ lf, float* __restrict__ outA,
                               float* __restrict__ outB, int nb, int L, int W, int bq,
                               const double* __restrict__ wqs){
  int idx = blockIdx.x*blockDim.x + threadIdx.x;
  int total = nb*L*W*W;
  if(idx >= total) return;
  int q = idx % W;
  int p = (idx/W) % W;
  int l = (idx/(W*W)) % L;
  int j = idx/(W*W*L);
  int cw = (W-1)/2;
  int mh = p - cw, nh = q - cw;
  double s = 0.0;
  if(iabs_(mh) <= l && iabs_(nh) <= l){
    double beta = PI_D*(2*j+1)/(4.0*bq);
    double cb = cos(0.5*beta), sb = sin(0.5*beta);
    double lcb = log(cb), lsb = log(sb);
    int k0 = (nh - mh > 0) ? (nh - mh) : 0;
    int a1 = l + nh, b1 = l - mh;
    int k1 = (a1 < b1) ? a1 : b1;
    for(int k = k0; k <= k1; ++k){
      double logc = 0.5*(lf[l+mh] + lf[l-mh] + lf[l+nh] + lf[l-nh])
                    - lf[l+nh-k] - lf[k] - lf[mh-nh+k] - lf[l-mh-k];
      double term = exp(logc + (double)(2*l + nh - mh - 2*k)*lcb + (double)(mh - nh + 2*k)*lsb);
      s += ((mh - nh + k) & 1) ? -term : term;
    }
  }
  outA[idx] = (float)(s*(double)(2*l+1));
  outB[idx] = (float)(s*wqs[j]);
}

// K tables for fused GN->conv links
__global__ void k_ktab(const float* __restrict__ Wx, const float* __restrict__ Wi,
                       float* __restrict__ K, float* __restrict__ KB,
                       int Lout, int Lz, int Lfull, int Mt, int M, int off, int nj){
  int MtMt = Mt*Mt;
  int total = Lout*Lz*MtMt;
  int idx = blockIdx.x*blockDim.x + threadIdx.x;
  if(idx >= total) return;
  int pq = idx % MtMt;
  int lp = (idx/MtMt) % Lz;
  int l = idx/(MtMt*Lz);
  int p = pq/Mt, q = pq - p*Mt;
  int pg = p + off, qg = q + off;
  float sA = 0.f, sB = 0.f;
  for(int j = 0; j < nj; ++j){
    float wx = Wx[(((size_t)j*Lfull + l)*M + pg)*M + qg];
    sA += wx * Wi[(((size_t)j*Lfull + lp)*M + pg)*M + qg];
    sB += wx * Wi[(((size_t)j*Lfull + lp)*M + (M-1-pg))*M + (M-1-qg)];
  }
  K[idx] = sA;
  KB[idx] = sB;
}

__global__ void k_wxdc(const float* __restrict__ Wx, float* __restrict__ dc,
                       int Lout, int Lfull, int M, int nj){
  int l = threadIdx.x;
  if(l >= Lout) return;
  int c0 = (M-1)/2;
  float s = 0.f;
  for(int j = 0; j < nj; ++j)
    s += Wx[(((size_t)j*Lfull + l)*M + c0)*M + c0];
  dc[l] = s;
}

// ======================= layer-0 (S2) kernels =======================
__global__ void k_fft0(const float* __restrict__ x, cplx* __restrict__ xf, const cplx* __restrict__ E0f){
  int idx = blockIdx.x*blockDim.x + threadIdx.x;
  if(idx >= 1536*31) return;
  int m = idx % 31;
  int r = idx / 31;
  const float* xr = x + (size_t)r*64;
  float sr = 0.f, si = 0.f;
  for(int a = 0; a < 64; ++a){
    cplx e = E0f[m*64 + a];
    float v = xr[a];
    sr += v*e.x; si += v*e.y;
  }
  xf[idx] = make_float2(sr*(1.f/64.f), si*(1.f/64.f));
}

__global__ void k_what0(const float* __restrict__ w0, const cplx* __restrict__ E0f, cplx* __restrict__ what0){
  int idx = blockIdx.x*blockDim.x + threadIdx.x;
  if(idx >= 96*2*31) return;
  int m = idx % 31;
  int bi = (idx/31) & 1;
  int oi = idx/62;
  const float* wr = w0 + (size_t)oi*128 + bi*64;
  float sr = 0.f, si = 0.f;
  for(int a = 0; a < 64; ++a){
    cplx e = E0f[m*64 + a];
    float v = wr[a];
    sr += v*e.x; si += v*e.y;
  }
  what0[idx] = make_float2(sr, si);
}

__global__ void k_X0(const cplx* __restrict__ xf, const float* __restrict__ d032w,
                     cplx* __restrict__ X0){
  int idx = blockIdx.x*blockDim.x + threadIdx.x;
  if(idx >= 24*16*31) return;
  int m = idx % 31;
  int l = (idx/31) % 16;
  int ci = idx/(31*16);
  float sx = 0.f, sy = 0.f;
  if(iabs_(m-15) <= l){
    for(int j = 0; j < 64; ++j){
      float d = d032w[((size_t)j*16 + l)*31 + m];
      cplx v = xf[((size_t)ci*64 + j)*31 + m];
      sx += d*v.x; sy += d*v.y;
    }
  }
  X0[idx] = make_float2(sx, sy);
}

__global__ void k_Psi0(const cplx* __restrict__ what0, const float* __restrict__ dg32, cplx* __restrict__ Psi0){
  int idx = blockIdx.x*blockDim.x + threadIdx.x;
  if(idx >= 96*16*31) return;
  int m = idx % 31;
  int l = (idx/31) % 16;
  int oi = idx/(31*16);
  float sx = 0.f, sy = 0.f;
  if(iabs_(m-15) <= l){
    for(int bi = 0; bi < 2; ++bi){
      float d = dg32[((size_t)bi*16 + l)*31 + m];
      cplx v = what0[((size_t)oi*2 + bi)*31 + m];
      sx += d*v.x; sy += d*v.y;
    }
  }
  Psi0[idx] = make_float2(sx, sy);
}

__global__ void k_Z0(const cplx* __restrict__ X0, const cplx* __restrict__ Psi0, cplx* __restrict__ Z){
  int idx = blockIdx.x*blockDim.x + threadIdx.x;
  if(idx >= 8*32*16*961) return;
  int q = idx % 31;
  int p = (idx/31) % 31;
  int l = (idx/961) % 16;
  int o = (idx/(961*16)) % 32;
  int c = idx/(961*16*32);
  float sx = 0.f, sy = 0.f;
  if(iabs_(p-15) <= l && iabs_(q-15) <= l){
    for(int i = 0; i < 3; ++i){
      cplx a = X0[(((size_t)c*3 + i)*16 + l)*31 + p];
      cplx b = Psi0[(((size_t)o*3 + i)*16 + l)*31 + q];
      sx += a.x*b.x + a.y*b.y;
      sy += a.y*b.x - a.x*b.y;
    }
  }
  Z[idx] = make_float2(sx, sy);
}

// ============ j-batched SO3 inverse FFT, Hermitian-halved everywhere ============
template<int JB, int STAT>
__global__ void k_ifft_b2(const cplx* __restrict__ Zt, const float* __restrict__ Wst,
                          const cplx* __restrict__ E, float* __restrict__ out,
                          float2* __restrict__ part, int b){
  int M = 2*b-1, n2 = 2*b, Mp = n2, cw = b-1;
  int hg = b/4;
  int gc = n2/4;
  int Tst = b+1;
  int MM = M*M, HH = (MM+1)/2;
  extern __shared__ char smem[];
  cplx* Es = (cplx*)smem;
  cplx* gt = Es + M*n2;
  __shared__ float2 redw[16];
  int nj = n2/JB;
  int j0 = (blockIdx.x % nj)*JB;
  int co = blockIdx.x / nj;
  int tid = threadIdx.x, bd = blockDim.x;
  for(int t = tid; t < M*n2; t += bd) Es[t] = E[t];
  const cplx* Zp = Zt + (size_t)co*b*MM;
  float a1 = 0.f, a2c = 0.f;
  for(int t = tid; t < HH; t += bd){
    int p = t/M, q = t - p*M;
    int lmin = iabs_(p-cw); int l2 = iabs_(q-cw); if(l2 > lmin) lmin = l2;
    float sx[JB], sy[JB];
    #pragma unroll
    for(int s = 0; s < JB; ++s){ sx[s] = 0.f; sy[s] = 0.f; }
    for(int l = lmin; l < b; ++l){
      cplx z = Zp[(size_t)l*MM + t];
      #pragma unroll
      for(int s = 0; s < JB; ++s){
        float w = Wst[((size_t)(j0+s)*b + l)*MM + t];
        sx[s] += w*z.x; sy[s] += w*z.y;
      }
    }
    int pm = M-1-p, qm = M-1-q;
    bool ism = (t < HH-1);
    float wgt = ism ? 2.f : 1.f;
    #pragma unroll
    for(int s = 0; s < JB; ++s){
      gt[s*M*Mp + p*Mp + q] = make_float2(sx[s], sy[s]);
      if(ism) gt[s*M*Mp + pm*Mp + qm] = make_float2(sx[s], -sy[s]);
      if(STAT){
        a2c += wgt*(sx[s]*sx[s] + sy[s]*sy[s]);
        if(!ism) a1 += sx[s];
      }
    }
  }
  if(STAT){
    for(int o = 32; o > 0; o >>= 1){ a1 += __shfl_down(a1, o); a2c += __shfl_down(a2c, o); }
    if((tid & 63) == 0) redw[tid>>6] = make_float2(a1, a2c);
  }
  __syncthreads();
  int tpj = b*gc;
  int slab = tid / tpj, tl = tid - slab*tpj;
  int a2i = tl/hg, dg = tl - a2i*hg; int d0 = 4*dg;
  float Tx[4]={0,0,0,0}, Ty[4]={0,0,0,0};
  {
    const cplx* gts = gt + slab*M*Mp;
    for(int p = 0; p < M; ++p){
      cplx e = Es[p*n2 + a2i];
      const cplx* gr = gts + p*Mp + cw + d0;
      #pragma unroll
      for(int u = 0; u < 4; ++u){
        cplx g = gr[u];
        Tx[u] += g.x*e.x - g.y*e.y;
        Ty[u] += g.x*e.y + g.y*e.x;
      }
    }
  }
  __syncthreads();
  if(STAT && tid == 0){
    float s1 = 0.f, s2 = 0.f;
    int nw = bd >> 6;
    for(int w = 0; w < nw; ++w){ s1 += redw[w].x; s2 += redw[w].y; }
    part[blockIdx.x] = make_float2(s1, s2);
  }
  {
    cplx* Tts = gt + slab*M*Mp;
    #pragma unroll
    for(int u = 0; u < 4; ++u)
      Tts[a2i*Tst + d0+u] = make_float2(Tx[u], Ty[u]);
  }
  __syncthreads();
  {
    int a = tl/gc, gg = tl - a*gc; int g0 = 4*gg;
    const cplx* T0 = gt + slab*M*Mp + a*Tst;
    const cplx* T1 = gt + slab*M*Mp + (a+b)*Tst;
    float t00 = T0[0].x, t10 = T1[0].x;
    float S0[4] = {t00,t00,t00,t00}, S1[4] = {t10,t10,t10,t10};
    for(int d = 1; d < b; ++d){
      const float4* e4 = (const float4*)(Es + (cw+d)*n2 + g0);
      float4 ea = e4[0], eb = e4[1];
      cplx t0 = T0[d], t1 = T1[d];
      float t0x = 2.f*t0.x, t0y = 2.f*t0.y, t1x = 2.f*t1.x, t1y = 2.f*t1.y;
      S0[0] += t0x*ea.x - t0y*ea.y;
      S0[1] += t0x*ea.z - t0y*ea.w;
      S0[2] += t0x*eb.x - t0y*eb.y;
      S0[3] += t0x*eb.z - t0y*eb.w;
      S1[0] += t1x*ea.x - t1y*ea.y;
      S1[1] += t1x*ea.z - t1y*ea.w;
      S1[2] += t1x*eb.x - t1y*eb.y;
      S1[3] += t1x*eb.z - t1y*eb.w;
    }
    float* op0 = out + (size_t)co*n2*n2*n2 + (size_t)(j0+slab)*n2*n2 + a*n2 + g0;
    float* op1 = op0 + (size_t)b*n2;
    *(float4*)op0 = make_float4(S0[0],S0[1],S0[2],S0[3]);
    *(float4*)op1 = make_float4(S1[0],S1[1],S1[2],S1[3]);
  }
}

// small (b=4) ifft + optional fused Parseval stats
__global__ void k_ifft_s(const cplx* __restrict__ Zt, const float* __restrict__ Wst,
                         const cplx* __restrict__ E, float* __restrict__ out,
                         float2* __restrict__ part, int stat, int b){
  int M = 2*b-1, n2 = 2*b, cw = b-1;
  extern __shared__ char smem[];
  cplx* gt = (cplx*)smem;
  cplx* Tt = gt + M*M;
  int blk = blockIdx.x;
  int j = blk % n2;
  int co = blk / n2;
  const cplx* Zp = Zt + (size_t)co * b * M * M;
  for(int t = threadIdx.x; t < M*M; t += blockDim.x){
    int p = t / M, q = t % M;
    int lmin = iabs_(p-cw); int l2 = iabs_(q-cw); if(l2 > lmin) lmin = l2;
    float sx = 0.f, sy = 0.f;
    for(int l = lmin; l < b; ++l){
      float w = Wst[(((size_t)j*b + l)*M + p)*M + q];
      cplx z = Zp[((size_t)l*M + p)*M + q];
      sx += w*z.x; sy += w*z.y;
    }
    gt[t] = make_float2(sx, sy);
  }
  __syncthreads();
  if(stat){
    int MM = M*M, center = (MM-1)/2;
    float a1 = 0.f, a2 = 0.f;
    for(int t = threadIdx.x; t < MM; t += blockDim.x){
      cplx g = gt[t];
      cplx m = gt[MM-1-t];
      float hx = 0.5f*(g.x + m.x);
      float hy = 0.5f*(g.y - m.y);
      a2 += hx*hx + hy*hy;
      if(t == center) a1 += g.x;
    }
    for(int o = 32; o > 0; o >>= 1){ a1 += __shfl_down(a1, o); a2 += __shfl_down(a2, o); }
    if(threadIdx.x == 0) part[blockIdx.x] = make_float2(a1, a2);
  }
  for(int t = threadIdx.x; t < n2*M; t += blockDim.x){
    int a = t / M, q = t % M;
    float sx = 0.f, sy = 0.f;
    for(int p = 0; p < M; ++p){
      cplx e = E[p*n2 + a];
      cplx g = gt[p*M + q];
      sx += g.x*e.x - g.y*e.y;
      sy += g.x*e.y + g.y*e.x;
    }
    Tt[t] = make_float2(sx, sy);
  }
  __syncthreads();
  float* op = out + (size_t)co*n2*n2*n2 + (size_t)j*n2*n2;
  for(int t = threadIdx.x; t < n2*n2; t += blockDim.x){
    int a = t / n2, g = t % n2;
    float s = 0.f;
    for(int q = 0; q < M; ++q){
      cplx e = E[q*n2 + g];
      cplx T = Tt[a*M + q];
      s += T.x*e.x - T.y*e.y;
    }
    op[t] = s;
  }
}

// ===== gstat: Hermitian-halved, register-only =====
template<int JB>
__global__ void k_gstat(const cplx* __restrict__ Zt, const float* __restrict__ Wst,
                        float2* __restrict__ part, int b){
  int M = 2*b-1, n2 = 2*b, cw = b-1;
  int MM = M*M, HH = (MM+1)/2;
  __shared__ float2 red[256];
  int nj = n2/JB;
  int j0 = (blockIdx.x % nj)*JB;
  int co = blockIdx.x / nj;
  int tid = threadIdx.x, bd = blockDim.x;
  const cplx* Zp = Zt + (size_t)co*b*MM;
  float a1 = 0.f, a2 = 0.f;
  for(int t = tid; t < HH; t += bd){
    int p = t/M, q = t - p*M;
    int lmin = iabs_(p-cw); int l2 = iabs_(q-cw); if(l2 > lmin) lmin = l2;
    float sx[JB], sy[JB];
    #pragma unroll
    for(int s = 0; s < JB; ++s){ sx[s] = 0.f; sy[s] = 0.f; }
    for(int l = lmin; l < b; ++l){
      cplx z = Zp[(size_t)l*MM + t];
      #pragma unroll
      for(int s = 0; s < JB; ++s){
        float w = Wst[((size_t)(j0+s)*b + l)*MM + t];
        sx[s] += w*z.x; sy[s] += w*z.y;
      }
    }
    float wgt = (t < HH-1) ? 2.f : 1.f;
    #pragma unroll
    for(int s = 0; s < JB; ++s){
      a2 += wgt*(sx[s]*sx[s] + sy[s]*sy[s]);
      if(t == HH-1) a1 += sx[s];
    }
  }
  red[tid] = make_float2(a1, a2);
  __syncthreads();
  for(int o = 128; o > 0; o >>= 1){
    if(tid < o){ red[tid].x += red[tid+o].x; red[tid].y += red[tid+o].y; }
    __syncthreads();
  }
  if(tid == 0) part[blockIdx.x] = red[0];
}

// GN-style finalize
__global__ void k_gstat_fin(const float2* __restrict__ part, float2* __restrict__ st,
                            int N, int Cch, int G, int nj, float denom_inv){
  int gi = threadIdx.x;
  if(gi >= N*G) return;
  int n = gi/G, grp = gi - n*G;
  int cpg = Cch/G;
  double s1 = 0.0, s2 = 0.0;
  for(int cc = 0; cc < cpg; ++cc){
    int co = n*Cch + grp*cpg + cc;
    for(int jg = 0; jg < nj; ++jg){
      float2 v = part[co*nj + jg];
      s1 += v.x; s2 += v.y;
    }
  }
  double mu = s1*denom_inv;
  double e2 = s2*denom_inv;
  st[gi] = make_float2((float)mu, (float)(1.0/sqrt(e2 - mu*mu + 1e-5)));
}

// BN-style finalize
__global__ void k_gstat_finB(const float2* __restrict__ part, float2* __restrict__ st,
                             int N, int C, int nj, float denom_inv){
  int c = threadIdx.x;
  if(c >= C) return;
  double s1 = 0.0, s2 = 0.0;
  for(int n = 0; n < N; ++n)
    for(int jg = 0; jg < nj; ++jg){
      float2 v = part[(n*C + c)*nj + jg];
      s1 += v.x; s2 += v.y;
    }
  double mu = s1*denom_inv;
  double e2 = s2*denom_inv;
  st[c] = make_float2((float)mu, (float)(1.0/sqrt(e2 - mu*mu + 1e-5)));
}

// ===== k_xk: fused ifft->GN(affine)->fft2->Xstep via K tables =====
__global__ void k_xk(const cplx* __restrict__ Z, const float* __restrict__ K,
                     const float* __restrict__ KB, const float* __restrict__ WxDC,
                     const float2* __restrict__ st, const float* __restrict__ gam,
                     const float* __restrict__ bet, cplx* __restrict__ X,
                     int CI, int Cch, int G, int Lout, int Lz, int Mt, int M, int off){
  int MtMt = Mt*Mt;
  int total = CI*MtMt;
  int idx = blockIdx.x*blockDim.x + threadIdx.x;
  if(idx >= total) return;
  int pq = idx % MtMt;
  int ci = idx/MtMt;
  int p = pq/Mt, q = pq - p*Mt;
  int cwt = (Mt-1)/2;
  int dp = iabs_(p-cwt), dq = iabs_(q-cwt);
  int lmin = dp > dq ? dp : dq;
  int n = ci/Cch, c = ci - n*Cch;
  int cpg = Cch/G;
  float2 sv = st[n*G + c/cpg];
  float sc = sv.y*gam[c];
  float tc = bet[c] - sv.x*sc;
  int pg = p + off, qg = q + off;
  const cplx* Za = Z + (size_t)ci*Lz*M*M + (size_t)pg*M + qg;
  const cplx* Zb = Z + (size_t)ci*Lz*M*M + (size_t)(M-1-pg)*M + (M-1-qg);
  for(int l = 0; l < Lout; ++l){
    cplx o = make_float2(0.f, 0.f);
    if(l >= lmin){
      float Ax=0.f, Ay=0.f, Bx=0.f, By=0.f;
      const float* Kl = K + ((size_t)l*Lz)*MtMt + pq;
      const float* KBl = KB + ((size_t)l*Lz)*MtMt + pq;
      for(int lp = lmin; lp < Lz; ++lp){
        float k = Kl[(size_t)lp*MtMt];
        float kb = KBl[(size_t)lp*MtMt];
        cplx za = Za[(size_t)lp*M*M];
        cplx zb = Zb[(size_t)lp*M*M];
        Ax += k*za.x; Ay += k*za.y;
        Bx += kb*zb.x; By += kb*zb.y;
      }
      o.x = 0.5f*sc*(Ax + Bx);
      o.y = 0.5f*sc*(Ay - By);
      if(dp == 0 && dq == 0) o.x += tc*WxDC[l];
    }
    X[((size_t)(ci*Lout + l)*Mt + p)*Mt + q] = o;
  }
}

// ======================= batched forward 2D DFT, Hermitian-halved =======================
// Both stages use full-slab lane compaction: 2 outputs/thread, zero masked lanes.
__global__ void k_fft2_b(const float* __restrict__ f, cplx* __restrict__ hf,
                         const cplx* __restrict__ E, int b, int Mt, int JB,
                         const float2* __restrict__ st, const float* __restrict__ gam,
                         const float* __restrict__ bet, int Cch, int cpg, int relu,
                         const float* __restrict__ f2, const float2* __restrict__ bst,
                         const float* __restrict__ bga, const float* __restrict__ bbe){
  int M = 2*b-1, n2 = 2*b;
  int off = (M - Mt)/2;
  int ng = (Mt+3)/4, MtP = 4*ng;
  int cwt = (Mt-1)/2;
  int dh = (Mt+1)/2;
  int hg2 = dh/2;          // stage-A d-groups of 2
  int ngB = MtP/2;         // stage-B q-groups of 2
  int fs = n2+1, es = n2+1;
  int tpj = n2*hg2;        // = dh*ngB = threads per slab, all active
  extern __shared__ char smem[];
  float* ft = (float*)smem;                       // JB*n2*fs
  cplx* Ft  = (cplx*)(ft + JB*n2*fs);             // JB*n2*MtP
  cplx* EsT = Ft + (size_t)JB*n2*MtP;             // n2*dh
  cplx* Es  = EsT + (size_t)n2*dh;                // Mt*es
  int nj = n2/JB;
  int ci = blockIdx.x / nj, jg = blockIdx.x % nj;
  int tid = threadIdx.x, bd = blockDim.x;
  float mu = 0.f, inv = 1.f, ga = 1.f, be = 0.f;
  float bmu = 0.f, binv = 1.f, bga_ = 1.f, bbe_ = 0.f;
  if(st){
    int c = ci % Cch, n = ci / Cch;
    float2 sv = st[n*(Cch/cpg) + c/cpg];
    mu = sv.x; inv = sv.y; ga = gam[c]; be = bet[c];
  }
  if(f2){
    int c = ci % Cch;
    float2 bv = bst[c];
    bmu = bv.x; binv = bv.y; bga_ = bga[c]; bbe_ = bbe[c];
  }
  const float* fbase = f + ((size_t)ci*n2 + (size_t)jg*JB)*n2*n2;
  const float* f2base = f2 ? (f2 + ((size_t)ci*n2 + (size_t)jg*JB)*n2*n2) : nullptr;
  for(int t = tid; t < JB*n2*n2; t += bd){
    int sj = t/(n2*n2); int r = t - sj*n2*n2;
    float v = fbase[(size_t)sj*n2*n2 + r];
    if(st){ v = (v - mu)*inv*ga + be; if(relu) v = fmaxf(v, 0.f); }
    if(f2){
      float vb = (f2base[(size_t)sj*n2*n2 + r] - bmu)*binv*bga_ + bbe_;
      v = fmaxf(v + vb, 0.f);
    }
    ft[sj*n2*fs + (r/n2)*fs + (r%n2)] = v;
  }
  for(int t = tid; t < n2*dh; t += bd){
    int g = t/dh, d = t - g*dh;
    EsT[t] = E[(cwt+d+off)*n2 + g];
  }
  for(int t = tid; t < Mt*n2; t += bd){
    int r = t/n2, a = t - r*n2;
    Es[r*es + a] = E[(r+off)*n2 + a];
  }
  __syncthreads();
  int slab = tid / tpj, tl = tid - slab*tpj;
  // ---- stage A: row DFT, 2 d per thread, all lanes active ----
  {
    int a = tl/hg2, dg = tl - a*hg2;
    int d0 = 2*dg;
    const float* fr = ft + slab*n2*fs + a*fs;
    float ax0=0.f, ax1=0.f, ay0=0.f, ay1=0.f;
    for(int g = 0; g < n2; ++g){
      float v = fr[g];
      const float4* e4 = (const float4*)(EsT + g*dh + d0);
      float4 ea = e4[0];
      ax0 += v*ea.x; ay0 -= v*ea.y;
      ax1 += v*ea.z; ay1 -= v*ea.w;
    }
    cplx* Fp = Ft + slab*n2*MtP + a*MtP;
    float vx[2] = {ax0, ax1};
    float vy[2] = {ay0, ay1};
    #pragma unroll
    for(int u = 0; u < 2; ++u){
      int d = d0+u;
      Fp[cwt+d] = make_float2(vx[u], vy[u]);
      if(d > 0) Fp[cwt-d] = make_float2(vx[u], -vy[u]);
    }
  }
  __syncthreads();
  // ---- stage B: column DFT, 2 q per thread, all lanes active ----
  {
    int ph = tl/ngB, qg = tl - ph*ngB; int q0 = 2*qg;
    int p = cwt + ph;
    float ax0=0.f, ax1=0.f, ay0=0.f, ay1=0.f;
    const cplx* Fb = Ft + slab*n2*MtP;
    for(int a = 0; a < n2; ++a){
      cplx e = Es[p*es + a];
      const float4* F4 = (const float4*)(Fb + a*MtP + q0);
      float4 Fa = F4[0];
      ax0 += e.x*Fa.x + e.y*Fa.y;  ay0 += e.x*Fa.y - e.y*Fa.x;
      ax1 += e.x*Fa.z + e.y*Fa.w;  ay1 += e.x*Fa.w - e.y*Fa.z;
    }
    float invn = 1.0f/((float)n2*(float)n2);
    int j = jg*JB + slab;
    cplx* hp = hf + ((size_t)ci*n2 + j)*Mt*Mt + p*Mt;
    cplx* hpm = hf + ((size_t)ci*n2 + j)*Mt*Mt + (cwt-ph)*Mt;
    float vx[2] = {ax0, ax1};
    float vy[2] = {ay0, ay1};
    #pragma unroll
    for(int u = 0; u < 2; ++u){
      int q = q0+u;
      if(q < Mt){
        hp[q] = make_float2(vx[u]*invn, vy[u]*invn);
        if(ph > 0) hpm[Mt-1-q] = make_float2(vx[u]*invn, -vy[u]*invn);
      }
    }
  }
}

// X Hermitian-halved + l-split
template<int LOUT>
__global__ void k_Xstep_h(const cplx* __restrict__ hf, const float* __restrict__ Wst,
                          cplx* __restrict__ X, int b, int Mt, int CI, int Ltot){
  int M = 2*b-1, n2 = 2*b, MM = M*M;
  int off = (M - Mt)/2, cw = (Mt-1)/2;
  int MtMt = Mt*Mt, HH = (MtMt+1)/2;
  int lbase = blockIdx.y*LOUT;
  int total = CI*HH;
  int idx = blockIdx.x*blockDim.x + threadIdx.x;
  if(idx >= total) return;
  int t = idx % HH;
  int ci = idx/HH;
  int p = t / Mt, q = t - p*Mt;
  int pm = Mt-1-p, qm = Mt-1-q;
  bool ism = (t < HH-1);
  float sgn = ((p + q) & 1) ? -1.f : 1.f;
  int dp = iabs_(p-cw), dq = iabs_(q-cw);
  int lmin = dp > dq ? dp : dq;
  float ax[LOUT], ay[LOUT];
  #pragma unroll
  for(int li = 0; li < LOUT; ++li){ ax[li] = 0.f; ay[li] = 0.f; }
  int wpq = (p+off)*M + (q+off);
  const cplx* hp = hf + (size_t)ci*n2*MtMt + (size_t)p*Mt + q;
  for(int j = 0; j < n2; ++j){
    cplx v = hp[(size_t)j*MtMt];
    const float* wj = Wst + ((size_t)j*b + lbase)*MM + wpq;
    #pragma unroll
    for(int li = 0; li < LOUT; ++li){
      if(lbase + li >= lmin){
        float w = wj[(size_t)li*MM];
        ax[li] += w*v.x; ay[li] += w*v.y;
      }
    }
  }
  cplx* xp = X + ((size_t)ci*Ltot + lbase)*MtMt;
  #pragma unroll
  for(int li = 0; li < LOUT; ++li){
    if(lbase + li >= lmin){
      xp[(size_t)li*MtMt + p*Mt + q] = make_float2(ax[li], ay[li]);
      if(ism) xp[(size_t)li*MtMt + pm*Mt + qm] = make_float2(sgn*ax[li], -sgn*ay[li]);
    }else{
      xp[(size_t)li*MtMt + p*Mt + q] = make_float2(0.f, 0.f);
      if(ism) xp[(size_t)li*MtMt + pm*Mt + qm] = make_float2(0.f, 0.f);
    }
  }
}

__global__ void k_what(const float* __restrict__ w, cplx* __restrict__ what,
                       const cplx* __restrict__ E, int n2, int Mt, int off, int OI){
  int total = OI*2*Mt;
  int idx = blockIdx.x*blockDim.x + threadIdx.x;
  if(idx >= total) return;
  int p = idx % Mt;
  int bi = (idx/Mt) & 1;
  int oi = idx/(2*Mt);
  const float* wr = w + (size_t)oi*4*n2 + (size_t)bi*2*n2;
  float sr = 0.f, si = 0.f;
  for(int a = 0; a < n2; ++a){
    float v = wr[2*a] + wr[2*a+1];
    cplx e = E[(p+off)*n2 + a];
    sr += v*e.x; si -= v*e.y;
  }
  what[idx] = make_float2(sr, si);
}

// ---- ystep: Hermitian-halved (pp,qq) grid, both bi in one thread ----
__global__ void k_ystep_h(const cplx* __restrict__ X, const float* __restrict__ Dg,
                          cplx* __restrict__ Y, int CI, int Wt, int Wd, int Lx, int Ld){
  int l = blockIdx.z;
  int K21 = 2*l+1;
  int KK = K21*K21, HH = (KK+1)/2;
  int cw = (Wt-1)/2, cwd = (Wd-1)/2;
  int l0 = cw - l, l0d = cwd - l;
  int tot = CI*HH;
  int idx = blockIdx.x*blockDim.x + threadIdx.x;
  if(idx >= tot) return;
  int t = idx % HH;
  int ci = idx/HH;
  int pp = t/K21, qq = t - pp*K21;
  int ppm = K21-1-pp, qqm = K21-1-qq;
  bool ism = (t < HH-1);
  float sgn = ((pp + qq) & 1) ? -1.f : 1.f;
  const cplx* xp = X + (((size_t)ci*Lx + l)*Wt + (pp+l0))*Wt + l0;
  const float* dp0 = Dg + (((size_t)0*Ld + l)*Wd + (qq+l0d))*Wd + l0d;
  const float* dp1 = Dg + (((size_t)1*Ld + l)*Wd + (qq+l0d))*Wd + l0d;
  float s0x=0.f, s0y=0.f, s1x=0.f, s1y=0.f;
  for(int k = 0; k < K21; ++k){
    cplx v = xp[k];
    float d0 = dp0[k], d1 = dp1[k];
    s0x += d0*v.x; s0y += d0*v.y;
    s1x += d1*v.x; s1y += d1*v.y;
  }
  size_t yoff = (size_t)CI*2*((size_t)l*(2*l-1)*(2*l+1)/3);
  cplx* yb = Y + yoff + (size_t)ci*K21*2*K21;
  yb[(pp*2+0)*K21 + qq] = make_float2(s0x, s0y);
  yb[(pp*2+1)*K21 + qq] = make_float2(s1x, s1y);
  if(ism){
    yb[(ppm*2+0)*K21 + qqm] = make_float2(sgn*s0x, -sgn*s0y);
    yb[(ppm*2+1)*K21 + qqm] = make_float2(sgn*s1x, -sgn*s1y);
  }
}

// Z via 2D (c,o) register tile, Hermitian-halved (p,q) grid with SIGNED conj mirror
template<int NC, int NO>
__global__ void k_zstep2(const cplx* __restrict__ Y, const cplx* __restrict__ what,
                         cplx* __restrict__ Z, int C, int O, int I, int Wt){
  int l = blockIdx.z;
  int Lz = gridDim.z;
  int K21 = 2*l+1;
  int cw = (Wt-1)/2;
  int l0 = cw - l;
  int WW = Wt*Wt, HH = (WW+1)/2;
  int Cg = C/NC, Og = O/NO;
  int tot = Cg*Og*HH;
  int idx = blockIdx.x*blockDim.x + threadIdx.x;
  if(idx >= tot) return;
  int t = idx % HH;
  int og = (idx/HH) % Og;
  int cg = idx/(HH*Og);
  int p = t / Wt, q = t - p*Wt;
  int pm = Wt-1-p, qm = Wt-1-q;
  bool ism = (t < HH-1);
  float sgn = ((p + q) & 1) ? -1.f : 1.f;
  int c0 = cg*NC, o0 = og*NO;
  bool valid = (iabs_(p-cw) <= l) && (iabs_(q-cw) <= l);
  if(!valid){
    cplx z0 = make_float2(0.f, 0.f);
    #pragma unroll
    for(int a = 0; a < NC; ++a)
      #pragma unroll
      for(int tt = 0; tt < NO; ++tt){
        size_t base = (((size_t)(c0+a)*O + (o0+tt))*Lz + l)*Wt;
        Z[(base + p)*Wt + q] = z0;
        if(ism) Z[(base + pm)*Wt + qm] = z0;
      }
    return;
  }
  int pp = p - l0, qq = q - l0;
  size_t yoff = (size_t)C*I*2*((size_t)l*(2*l-1)*(2*l+1)/3);
  const cplx* yb = Y + yoff + ((size_t)pp*2)*K21 + qq;
  size_t yci = (size_t)K21*2*K21;
  const cplx* wb = what + q;
  float ax[NC][NO], ay[NC][NO];
  #pragma unroll
  for(int a = 0; a < NC; ++a)
    #pragma unroll
    for(int tt = 0; tt < NO; ++tt){ ax[a][tt] = 0.f; ay[a][tt] = 0.f; }
  for(int i = 0; i < I; ++i){
    cplx y0[NC], y1[NC];
    #pragma unroll
    for(int a = 0; a < NC; ++a){
      const cplx* yp = yb + (size_t)((c0+a)*I + i)*yci;
      y0[a] = yp[0];
      y1[a] = yp[K21];
    }
    #pragma unroll
    for(int tt = 0; tt < NO; ++tt){
      size_t wo = (size_t)(((o0+tt)*I + i)*2)*Wt;
      cplx w0 = wb[wo];
      cplx w1 = wb[wo + Wt];
      #pragma unroll
      for(int a = 0; a < NC; ++a){
        ax[a][tt] += y0[a].x*w0.x + y0[a].y*w0.y + y1[a].x*w1.x + y1[a].y*w1.y;
        ay[a][tt] += y0[a].y*w0.x - y0[a].x*w0.y + y1[a].y*w1.x - y1[a].x*w1.y;
      }
    }
  }
  #pragma unroll
  for(int a = 0; a < NC; ++a)
    #pragma unroll
    for(int tt = 0; tt < NO; ++tt){
      size_t base = (((size_t)(c0+a)*O + (o0+tt))*Lz + l)*Wt;
      Z[(base + p)*Wt + q] = make_float2(ax[a][tt], ay[a][tt]);
      if(ism) Z[(base + pm)*Wt + qm] = make_float2(sgn*ax[a][tt], -sgn*ay[a][tt]);
    }
}

__global__ void k_zid(const cplx* __restrict__ X, const float* __restrict__ w,
                      cplx* __restrict__ Z, int C, int O, int I, int Lz, int Wt, int Wx, int Lx){
  int total = C*O*Lz*Wt*Wt;
  int idx = blockIdx.x*blockDim.x + threadIdx.x;
  if(idx >= total) return;
  int q = idx % Wt;
  int p = (idx/Wt) % Wt;
  int l = (idx/(Wt*Wt)) % Lz;
  int o = (idx/(Wt*Wt*Lz)) % O;
  int c = idx/(Wt*Wt*Lz*O);
  int cw = (Wt-1)/2, offx = (Wx-Wt)/2;
  float sx = 0.f, sy = 0.f;
  if(iabs_(p-cw) <= l && iabs_(q-cw) <= l){
    for(int i = 0; i < I; ++i){
      cplx v = X[((((size_t)c*I + i)*Lx + l)*Wx + p + offx)*Wx + q + offx];
      float wv = w[o*I + i];
      sx += wv*v.x; sy += wv*v.y;
    }
  }
  Z[idx] = make_float2(sx, sy);
}

// fused: out[n,c] = sum_jag relu( relu(gn(a)) + bn(b) ) * wq[j] / 64
__global__ void k_integrate2(const float* __restrict__ a, const float* __restrict__ bb,
                             const float2* __restrict__ gst, const float* __restrict__ gga,
                             const float* __restrict__ gbe,
                             const float2* __restrict__ bst, const float* __restrict__ bga,
                             const float* __restrict__ bbe,
                             const double* __restrict__ wq4, float* __restrict__ out,
                             int C, int G){
  int nc = blockIdx.x;
  int n = nc / C, c = nc % C;
  int cpg = C/G;
  float2 gs = gst[n*G + c/cpg];
  float2 bs = bst[c];
  float ga_ = gga[c], ge = gbe[c], ba = bga[c], be = bbe[c];
  const float* ap = a + (size_t)nc*512;
  const float* bp = bb + (size_t)nc*512;
  float s = 0.f;
  for(int t = threadIdx.x; t < 512; t += 64){
    int j = t >> 6;
    float va = fmaxf((ap[t]-gs.x)*gs.y*ga_ + ge, 0.f);
    float vb = (bp[t]-bs.x)*bs.y*ba + be;
    float h = fmaxf(va + vb, 0.f);
    s += h * (float)wq4[j];
  }
  for(int o = 32; o > 0; o >>= 1) s += __shfl_down(s, o);
  if(threadIdx.x == 0) out[nc] = s * (1.f/64.f);
}

// ======================= launch =======================
extern "C" void kernel_launch(void* const* d_in, const int* in_sizes, int n_in,
                              void* d_out, int out_size, void* d_ws, size_t ws_size,
                              hipStream_t stream){
  const float* xin = (const float*)d_in[0];
  const float* w0p = (const float*)d_in[1];
  const float* g0p = (const float*)d_in[2];
  const float* b0p = (const float*)d_in[3];
  const float* w1ap = (const float*)d_in[4];
  const float* g1ap = (const float*)d_in[5];
  const float* b1ap = (const float*)d_in[6];
  const float* w1bp = (const float*)d_in[7];
  const float* g1bp = (const float*)d_in[8];
  const float* b1bp = (const float*)d_in[9];
  const float* w1sp = (const float*)d_in[10];
  const float* g1sp = (const float*)d_in[11];
  const float* b1sp = (const float*)d_in[12];
  const float* w2ap = (const float*)d_in[13];
  const float* g2ap = (const float*)d_in[14];
  const float* b2ap = (const float*)d_in[15];
  const float* w2bp = (const float*)d_in[16];
  const float* g2bp = (const float*)d_in[17];
  const float* b2bp = (const float*)d_in[18];
  const float* w2sp = (const float*)d_in[19];
  const float* g2sp = (const float*)d_in[20];
  const float* b2sp = (const float*)d_in[21];
  float* outp = (float*)d_out;

  char* ws = (char*)d_ws;
  size_t off = 0;
  auto alloc = [&](size_t bytes)->char*{
    char* p = ws + off;
    off = (off + bytes + 255) & ~(size_t)255;
    return p;
  };
  // tables (persistent)
  double* lf   = (double*)alloc(130*8);
  double* wq   = (double*)alloc(120*8);
  cplx* E16    = (cplx*)alloc(31*32*8);
  cplx* E8     = (cplx*)alloc(15*16*8);
  cplx* E4     = (cplx*)alloc(7*8*8);
  cplx* E0f    = (cplx*)alloc(31*64*8);
  float* d032w = (float*)alloc((size_t)64*16*31*4);
  float* dg32  = (float*)alloc((size_t)2*16*31*4);
  float* Wi16  = (float*)alloc((size_t)32*16*961*4);
  float* Wx16  = (float*)alloc((size_t)32*16*961*4);
  float* Dg16  = (float*)alloc((size_t)2*16*961*4);
  float* Wi8   = (float*)alloc((size_t)16*8*225*4);
  float* Wx8   = (float*)alloc((size_t)16*8*225*4);
  float* Dg8   = (float*)alloc((size_t)2*8*225*4);
  float* Wi4   = (float*)alloc((size_t)8*4*49*4);
  // K tables
  float* K16   = (float*)alloc((size_t)8*16*225*4);
  float* KB16  = (float*)alloc((size_t)8*16*225*4);
  float* K8    = (float*)alloc((size_t)4*8*49*4);
  float* KB8   = (float*)alloc((size_t)4*8*49*4);
  float* WxDC16= (float*)alloc(8*4);
  float* WxDC8 = (float*)alloc(4*4);
  // stat partials
  float2* part_f = (float2*)alloc(8192*8);
  float2* st_h0 = (float2*)alloc(256*8);
  float2* st_l1 = (float2*)alloc(256*8);
  float2* st_l2 = (float2*)alloc(256*8);
  float2* st_s1 = (float2*)alloc(256*8);
  float2* st_l3 = (float2*)alloc(256*8);
  float2* st_l4 = (float2*)alloc(256*8);
  float2* st_s2 = (float2*)alloc(256*8);
  // arenas
  char* A_ZHF = alloc((size_t)63*1024*1024);
  char* A_X   = alloc((size_t)32*1024*1024);
  char* A_H1  = alloc((size_t)34*1024*1024);
  char* A_H2  = alloc((size_t)34*1024*1024);
  char* A_S   = alloc((size_t)8*1024*1024);

  // phase aliases
  cplx* xf0    = (cplx*)(A_S);
  cplx* X0     = (cplx*)(A_S + (512<<10));
  cplx* what0  = (cplx*)(A_S + (768<<10));
  cplx* Psi0   = (cplx*)(A_S + (1<<20));
  cplx* Zt0    = (cplx*)A_ZHF;
  float* h0    = (float*)A_H1;
  cplx* hf1    = (cplx*)A_ZHF;
  cplx* X1     = (cplx*)A_X;
  cplx* what1a = (cplx*)A_S;
  cplx* Y1a    = (cplx*)A_H2;
  cplx* Z1a    = (cplx*)A_ZHF;
  cplx* X1b    = (cplx*)A_S;
  cplx* what1b = (cplx*)(A_S + (4<<20));
  cplx* Y1b    = (cplx*)A_H1;
  cplx* Z1b    = (cplx*)A_ZHF;
  float* left2 = (float*)A_H1;
  cplx* Z1s    = (cplx*)A_ZHF;
  float* sc1   = (float*)(A_H1 + (12<<20));
  cplx* hf2    = (cplx*)A_ZHF;
  cplx* X2     = (cplx*)A_X;
  cplx* what2a = (cplx*)A_S;
  cplx* Y2a    = (cplx*)A_H2;
  cplx* Z2a    = (cplx*)A_ZHF;
  cplx* X2b    = (cplx*)A_S;
  cplx* what2b = (cplx*)(A_S + (1<<20));
  cplx* Y2b    = (cplx*)(A_S + (2<<20));
  cplx* Z2b    = (cplx*)A_ZHF;
  float* left4 = (float*)A_H1;
  cplx* Z2s    = (cplx*)A_ZHF;
  float* sc2   = (float*)(A_H1 + (4<<20));

  auto ifftb2_smem = [](int b, int JB)->size_t{
    int M = 2*b-1, n2 = 2*b;
    return (size_t)(M*n2 + JB*M*n2)*8;
  };
  auto fft2b_smem = [](int b, int Mt, int JB)->size_t{
    int n2 = 2*b; int ng = (Mt+3)/4, MtP = 4*ng;
    int dh = (Mt+1)/2;
    return (size_t)(JB*n2*(n2+1))*4 + (size_t)(JB*n2*MtP)*8
         + (size_t)(n2*dh)*8 + (size_t)(Mt*(n2+1))*8;
  };

  // ---- tables ----
  k_tables<<<1,256,0,stream>>>(lf, wq);
  k_twiddle<<<(31*32+255)/256,256,0,stream>>>(E16, 31, 32, 15,  1.0);
  k_twiddle<<<1,256,0,stream>>>(E8, 15, 16, 7,  1.0);
  k_twiddle<<<1,64,0,stream>>>(E4, 7, 8, 3,  1.0);
  k_twiddle<<<(31*64+255)/256,256,0,stream>>>(E0f, 31, 64, 15, -1.0);
  k_wigner_col0<<<(64*16*31+255)/256,256,0,stream>>>(lf, d032w, 64, 16, 31, 0, 32, wq, 2);
  k_wigner_col0<<<(2*16*31+255)/256,256,0,stream>>>(lf, dg32, 2, 16, 31, 1, 0, wq, 0);
  k_wigner_full2<<<(32*16*961+255)/256,256,0,stream>>>(lf, Wi16, Wx16, 32, 16, 31, 16, wq+64);
  k_wigner_full<<<(2*16*961+255)/256,256,0,stream>>>(lf, Dg16, 2, 16, 31, 1, 0, wq, 0);
  k_wigner_full2<<<(16*8*225+255)/256,256,0,stream>>>(lf, Wi8, Wx8, 16, 8, 15, 8, wq+96);
  k_wigner_full<<<(2*8*225+255)/256,256,0,stream>>>(lf, Dg8, 2, 8, 15, 1, 0, wq, 0);
  k_wigner_full<<<(8*4*49+255)/256,256,0,stream>>>(lf, Wi4, 8, 4, 7, 0, 4, wq, 1);
  k_ktab<<<(8*16*225+255)/256,256,0,stream>>>(Wx16, Wi16, K16, KB16, 8, 16, 16, 15, 31, 8, 32);
  k_ktab<<<(4*8*49+255)/256,256,0,stream>>>(Wx8, Wi8, K8, KB8, 4, 8, 8, 7, 15, 4, 16);
  k_wxdc<<<1,64,0,stream>>>(Wx16, WxDC16, 8, 16, 31, 32);
  k_wxdc<<<1,64,0,stream>>>(Wx8, WxDC8, 4, 8, 15, 16);

  // ---- layer 0: s2_conv(x, w0, 32, 16); GN stats fused into ifft ----
  k_fft0<<<(1536*31+255)/256,256,0,stream>>>(xin, xf0, E0f);
  k_what0<<<(96*2*31+255)/256,256,0,stream>>>(w0p, E0f, what0);
  k_X0<<<(24*16*31+255)/256,256,0,stream>>>(xf0, d032w, X0);
  k_Psi0<<<(96*16*31+255)/256,256,0,stream>>>(what0, dg32, Psi0);
  k_Z0<<<(8*32*16*961+255)/256,256,0,stream>>>(X0, Psi0, Zt0);
  k_ifft_b2<4,1><<<8*32*8,512,ifftb2_smem(16,4),stream>>>(Zt0, Wi16, E16, h0, part_f, 16);
  k_gstat_fin<<<1,128,0,stream>>>(part_f, st_h0, 8, 32, 16, 8, 1.f/64.f);

  // ---- layer 1a: so3_conv(h, w1a, 16, 16) ----
  k_fft2_b<<<256*16,512,fft2b_smem(16,31,2),stream>>>(h0, hf1, E16, 16, 31, 2,
      st_h0, g0p, b0p, 32, 2, 1, nullptr, nullptr, nullptr, nullptr);
  { dim3 g((256*481+255)/256, 2);
    k_Xstep_h<8><<<g,256,0,stream>>>(hf1, Wx16, X1, 16, 31, 256, 16); }
  k_what<<<(1024*2*31+255)/256,256,0,stream>>>(w1ap, what1a, E16, 32, 31, 0, 1024);
  { dim3 g((256*481+255)/256,1,16);
    k_ystep_h<<<g,256,0,stream>>>(X1, Dg16, Y1a, 256, 31, 31, 16, 16); }
  { dim3 g((2*8*481+255)/256,1,16);
    k_zstep2<4,4><<<g,256,0,stream>>>(Y1a, what1a, Z1a, 8, 32, 32, 31); }
  k_gstat<8><<<256*4,256,0,stream>>>(Z1a, Wi16, part_f, 16);
  k_gstat_fin<<<1,128,0,stream>>>(part_f, st_l1, 8, 32, 16, 4, 1.f/64.f);
  k_xk<<<(256*225+255)/256,256,0,stream>>>(Z1a, K16, KB16, WxDC16,
                                           st_l1, g1ap, b1ap, X1b,
                                           256, 32, 16, 8, 16, 15, 31, 8);

  // ---- layer 1b: so3_conv(left, w1b, 16, 8); GN stats fused into ifft ----
  k_what<<<(2048*2*15+255)/256,256,0,stream>>>(w1bp, what1b, E16, 32, 15, 8, 2048);
  { dim3 g((256*113+255)/256,1,8);
    k_ystep_h<<<g,256,0,stream>>>(X1b, Dg16, Y1b, 256, 15, 31, 8, 16); }
  { dim3 g((4*16*113+255)/256,1,8);
    k_zstep2<2,4><<<g,256,0,stream>>>(Y1b, what1b, Z1b, 8, 64, 32, 15); }
  k_ifft_b2<16,1><<<8*64,512,ifftb2_smem(8,16),stream>>>(Z1b, Wi8, E8, left2, part_f, 8);
  k_gstat_fin<<<1,128,0,stream>>>(part_f, st_l2, 8, 64, 16, 1, 1.f/64.f);

  // ---- layer 1s: shortcut conv; BN stats fused into ifft ----
  k_zid<<<(8*64*8*225+255)/256,256,0,stream>>>(X1, w1sp, Z1s, 8, 64, 32, 8, 15, 31, 16);
  k_ifft_b2<16,1><<<8*64,512,ifftb2_smem(8,16),stream>>>(Z1s, Wi8, E8, sc1, part_f, 8);
  k_gstat_finB<<<1,128,0,stream>>>(part_f, st_s1, 8, 64, 1, 1.f/128.f);

  // ---- layer 2a: so3_conv(h, w2a, 8, 8); residual join fused into fft2 staging ----
  k_fft2_b<<<512*4,256,fft2b_smem(8,15,4),stream>>>(left2, hf2, E8, 8, 15, 4,
      st_l2, g1bp, b1bp, 64, 4, 1, sc1, st_s1, g1sp, b1sp);
  { dim3 g((512*113+255)/256, 2);
    k_Xstep_h<4><<<g,256,0,stream>>>(hf2, Wx8, X2, 8, 15, 512, 8); }
  k_what<<<(4096*2*15+255)/256,256,0,stream>>>(w2ap, what2a, E8, 16, 15, 0, 4096);
  { dim3 g((512*113+255)/256,1,8);
    k_ystep_h<<<g,256,0,stream>>>(X2, Dg8, Y2a, 512, 15, 15, 8, 8); }
  { dim3 g((4*16*113+255)/256,1,8);
    k_zstep2<2,4><<<g,256,0,stream>>>(Y2a, what2a, Z2a, 8, 64, 64, 15); }
  k_gstat<16><<<512,256,0,stream>>>(Z2a, Wi8, part_f, 8);
  k_gstat_fin<<<1,128,0,stream>>>(part_f, st_l3, 8, 64, 16, 1, 1.f/64.f);
  k_xk<<<(512*49+255)/256,256,0,stream>>>(Z2a, K8, KB8, WxDC8,
                                          st_l3, g2ap, b2ap, X2b,
                                          512, 64, 16, 4, 8, 7, 15, 4);

  // ---- layer 2b: so3_conv(left, w2b, 8, 4); GN stats fused into ifft ----
  k_what<<<(8192*2*7+255)/256,256,0,stream>>>(w2bp, what2b, E8, 16, 7, 4, 8192);
  { dim3 g((512*25+255)/256,1,4);
    k_ystep_h<<<g,256,0,stream>>>(X2b, Dg8, Y2b, 512, 7, 15, 4, 8); }
  { dim3 g((8*64*25+255)/256,1,4);
    k_zstep2<1,2><<<g,256,0,stream>>>(Y2b, what2b, Z2b, 8, 128, 64, 7); }
  k_ifft_s<<<8*128*8,64,(49+56)*8,stream>>>(Z2b, Wi4, E4, left4, part_f, 1, 4);
  k_gstat_fin<<<1,256,0,stream>>>(part_f, st_l4, 8, 128, 32, 8, 1.f/32.f);

  // ---- layer 2s: shortcut conv; BN stats fused into ifft ----
  k_zid<<<(8*128*4*49+255)/256,256,0,stream>>>(X2, w2sp, Z2s, 8, 128, 64, 4, 7, 15, 8);
  k_ifft_s<<<8*128*8,64,(49+56)*8,stream>>>(Z2s, Wi4, E4, sc2, part_f, 1, 4);
  k_gstat_finB<<<1,128,0,stream>>>(part_f, st_s2, 8, 128, 8, 1.f/64.f);

  // ---- fused residual join + integrate ----
  k_integrate2<<<1024,64,0,stream>>>(left4, sc2, st_l4, g2bp, b2bp,
                                     st_s2, g2sp, b2sp, wq+112, outp, 128, 32);
}

// Round 20
// 935.925 us; speedup vs baseline: 1.5341x; 1.0141x over previous
//
#include <hip/hip_runtime.h>
#include <math.h>

typedef float2 cplx;
#define PI_D 3.14159265358979323846

__device__ __forceinline__ int iabs_(int v){ return v < 0 ? -v : v; }

// ======================= table kernels =======================
__global__ void k_tables(double* lf, double* wq){
  if(threadIdx.x == 0){
    lf[0] = 0.0;
    double acc = 0.0;
    for(int i = 1; i <= 128; ++i){ acc += log((double)i); lf[i] = acc; }
  }
  int t = threadIdx.x;
  int b, j, off;
  if(t < 64){ b = 32; j = t; off = 0; }
  else if(t < 96){ b = 16; j = t - 64; off = 64; }
  else if(t < 112){ b = 8; j = t - 96; off = 96; }
  else if(t < 120){ b = 4; j = t - 112; off = 112; }
  else return;
  double beta = PI_D * (2*j+1) / (4.0*b);
  double s = 0.0;
  for(int p = 0; p < b; ++p) s += sin((2*p+1)*beta) / (2*p+1);
  wq[off+j] = 2.0*PI_D/((double)b*b) * sin(beta) * s;
}

__global__ void k_twiddle(cplx* E, int nfreq, int n, int center, double sgn){
  int idx = blockIdx.x*blockDim.x + threadIdx.x;
  if(idx >= nfreq*n) return;
  int p = idx / n, a = idx % n;
  double ang = sgn * 2.0*PI_D * (double)(p-center) * (double)a / (double)n;
  E[idx] = make_float2((float)cos(ang), (float)sin(ang));
}

// Wigner-d, n=0 column only; smode: 0 none, 1 *(2l+1), 2 *wqs[j]
__global__ void k_wigner_col0(const double* __restrict__ lf, float* __restrict__ out,
                              int nb, int Lmax, int W, int mode, int bq,
                              const double* __restrict__ wqs, int smode){
  int idx = blockIdx.x*blockDim.x + threadIdx.x;
  int total = nb*Lmax*W;
  if(idx >= total) return;
  int m = idx % W;
  int l = (idx/W) % Lmax;
  int j = idx/(W*Lmax);
  int cw = (W-1)/2;
  int mh = m - cw;
  float r = 0.f;
  if(iabs_(mh) <= l){
    double beta = (mode==0) ? PI_D*(2*j+1)/(4.0*bq) : PI_D*(j+1)/16.0;
    double cb = cos(0.5*beta), sb = sin(0.5*beta);
    double lcb = log(cb), lsb = log(sb);
    int k0 = (mh < 0) ? -mh : 0;
    int k1 = (mh > 0) ? (l - mh) : l;
    double s = 0.0;
    for(int k = k0; k <= k1; ++k){
      double logc = 0.5*(lf[l+mh] + lf[l-mh] + 2.0*lf[l])
                    - lf[l-k] - lf[k] - lf[mh+k] - lf[l-mh-k];
      double term = exp(logc + (double)(2*l - mh - 2*k)*lcb + (double)(mh + 2*k)*lsb);
      s += ((mh + k) & 1) ? -term : term;
    }
    if(smode == 1) s *= (double)(2*l+1);
    else if(smode == 2) s *= wqs[j];
    r = (float)s;
  }
  out[idx] = r;
}

// Full Wigner-d; smode: 0 none, 1 *(2l+1), 2 *wqs[j]
// pack!=0: write j-packed layout [j/4][l][W*W][4]
__global__ void k_wigner_full(const double* __restrict__ lf, float* __restrict__ out,
                              int nb, int L, int W, int mode, int bq,
                              const double* __restrict__ wqs, int smode, int pack){
  int idx = blockIdx.x*blockDim.x + threadIdx.x;
  int total = nb*L*W*W;
  if(idx >= total) return;
  int q = idx % W;
  int p = (idx/W) % W;
  int l = (idx/(W*W)) % L;
  int j = idx/(W*W*L);
  int cw = (W-1)/2;
  int mh = p - cw, nh = q - cw;
  float r = 0.f;
  if(iabs_(mh) <= l && iabs_(nh) <= l){
    double beta = (mode==0) ? PI_D*(2*j+1)/(4.0*bq) : PI_D*(j+1)/16.0;
    double cb = cos(0.5*beta), sb = sin(0.5*beta);
    double lcb = log(cb), lsb = log(sb);
    int k0 = (nh - mh > 0) ? (nh - mh) : 0;
    int a1 = l + nh, b1 = l - mh;
    int k1 = (a1 < b1) ? a1 : b1;
    double s = 0.0;
    for(int k = k0; k <= k1; ++k){
      double logc = 0.5*(lf[l+mh] + lf[l-mh] + lf[l+nh] + lf[l-nh])
                    - lf[l+nh-k] - lf[k] - lf[mh-nh+k] - lf[l-mh-k];
      double term = exp(logc + (double)(2*l + nh - mh - 2*k)*lcb + (double)(mh - nh + 2*k)*lsb);
      s += ((mh - nh + k) & 1) ? -term : term;
    }
    if(smode == 1) s *= (double)(2*l+1);
    else if(smode == 2) s *= wqs[j];
    r = (float)s;
  }
  if(pack)
    out[(((size_t)(j>>2)*L + l)*(W*W) + (p*W+q))*4 + (j&3)] = r;
  else
    out[idx] = r;
}

// Merged: computes the Wigner series ONCE.
// outA = d*(2l+1) in j-PACKED layout [j/4][l][W*W][4]; outB = d*wqs[j] normal layout.
__global__ void k_wigner_full2(const double* __restrict__ lf, float* __restrict__ outA,
                               float* __restrict__ outB, int nb, int L, int W, int bq,
                               const double* __restrict__ wqs){
  int idx = blockIdx.x*blockDim.x + threadIdx.x;
  int total = nb*L*W*W;
  if(idx >= total) return;
  int q = idx % W;
  int p = (idx/W) % W;
  int l = (idx/(W*W)) % L;
  int j = idx/(W*W*L);
  int cw = (W-1)/2;
  int mh = p - cw, nh = q - cw;
  double s = 0.0;
  if(iabs_(mh) <= l && iabs_(nh) <= l){
    double beta = PI_D*(2*j+1)/(4.0*bq);
    double cb = cos(0.5*beta), sb = sin(0.5*beta);
    double lcb = log(cb), lsb = log(sb);
    int k0 = (nh - mh > 0) ? (nh - mh) : 0;
    int a1 = l + nh, b1 = l - mh;
    int k1 = (a1 < b1) ? a1 : b1;
    for(int k = k0; k <= k1; ++k){
      double logc = 0.5*(lf[l+mh] + lf[l-mh] + lf[l+nh] + lf[l-nh])
                    - lf[l+nh-k] - lf[k] - lf[mh-nh+k] - lf[l-mh-k];
      double term = exp(logc + (double)(2*l + nh - mh - 2*k)*lcb + (double)(mh - nh + 2*k)*lsb);
      s += ((mh - nh + k) & 1) ? -term : term;
    }
  }
  outA[(((size_t)(j>>2)*L + l)*(W*W) + (p*W+q))*4 + (j&3)] = (float)(s*(double)(2*l+1));
  outB[idx] = (float)(s*wqs[j]);
}

// K tables for fused GN->conv links; Wi is j-PACKED [j/4][Lfull][M*M][4], Wx normal
__global__ void k_ktab(const float* __restrict__ Wx, const float* __restrict__ Wi,
                       float* __restrict__ K, float* __restrict__ KB,
                       int Lout, int Lz, int Lfull, int Mt, int M, int off, int nj){
  int MtMt = Mt*Mt;
  int MM = M*M;
  int total = Lout*Lz*MtMt;
  int idx = blockIdx.x*blockDim.x + threadIdx.x;
  if(idx >= total) return;
  int pq = idx % MtMt;
  int lp = (idx/MtMt) % Lz;
  int l = idx/(MtMt*Lz);
  int p = pq/Mt, q = pq - p*Mt;
  int pg = p + off, qg = q + off;
  float sA = 0.f, sB = 0.f;
  for(int j = 0; j < nj; ++j){
    float wx = Wx[(((size_t)j*Lfull + l)*M + pg)*M + qg];
    sA += wx * Wi[(((size_t)(j>>2)*Lfull + lp)*MM + (pg*M + qg))*4 + (j&3)];
    sB += wx * Wi[(((size_t)(j>>2)*Lfull + lp)*MM + ((M-1-pg)*M + (M-1-qg)))*4 + (j&3)];
  }
  K[idx] = sA;
  KB[idx] = sB;
}

__global__ void k_wxdc(const float* __restrict__ Wx, float* __restrict__ dc,
                       int Lout, int Lfull, int M, int nj){
  int l = threadIdx.x;
  if(l >= Lout) return;
  int c0 = (M-1)/2;
  float s = 0.f;
  for(int j = 0; j < nj; ++j)
    s += Wx[(((size_t)j*Lfull + l)*M + c0)*M + c0];
  dc[l] = s;
}

// ======================= layer-0 (S2) kernels =======================
__global__ void k_fft0(const float* __restrict__ x, cplx* __restrict__ xf, const cplx* __restrict__ E0f){
  int idx = blockIdx.x*blockDim.x + threadIdx.x;
  if(idx >= 1536*31) return;
  int m = idx % 31;
  int r = idx / 31;
  const float* xr = x + (size_t)r*64;
  float sr = 0.f, si = 0.f;
  for(int a = 0; a < 64; ++a){
    cplx e = E0f[m*64 + a];
    float v = xr[a];
    sr += v*e.x; si += v*e.y;
  }
  xf[idx] = make_float2(sr*(1.f/64.f), si*(1.f/64.f));
}

__global__ void k_what0(const float* __restrict__ w0, const cplx* __restrict__ E0f, cplx* __restrict__ what0){
  int idx = blockIdx.x*blockDim.x + threadIdx.x;
  if(idx >= 96*2*31) return;
  int m = idx % 31;
  int bi = (idx/31) & 1;
  int oi = idx/62;
  const float* wr = w0 + (size_t)oi*128 + bi*64;
  float sr = 0.f, si = 0.f;
  for(int a = 0; a < 64; ++a){
    cplx e = E0f[m*64 + a];
    float v = wr[a];
    sr += v*e.x; si += v*e.y;
  }
  what0[idx] = make_float2(sr, si);
}

__global__ void k_X0(const cplx* __restrict__ xf, const float* __restrict__ d032w,
                     cplx* __restrict__ X0){
  int idx = blockIdx.x*blockDim.x + threadIdx.x;
  if(idx >= 24*16*31) return;
  int m = idx % 31;
  int l = (idx/31) % 16;
  int ci = idx/(31*16);
  float sx = 0.f, sy = 0.f;
  if(iabs_(m-15) <= l){
    for(int j = 0; j < 64; ++j){
      float d = d032w[((size_t)j*16 + l)*31 + m];
      cplx v = xf[((size_t)ci*64 + j)*31 + m];
      sx += d*v.x; sy += d*v.y;
    }
  }
  X0[idx] = make_float2(sx, sy);
}

__global__ void k_Psi0(const cplx* __restrict__ what0, const float* __restrict__ dg32, cplx* __restrict__ Psi0){
  int idx = blockIdx.x*blockDim.x + threadIdx.x;
  if(idx >= 96*16*31) return;
  int m = idx % 31;
  int l = (idx/31) % 16;
  int oi = idx/(31*16);
  float sx = 0.f, sy = 0.f;
  if(iabs_(m-15) <= l){
    for(int bi = 0; bi < 2; ++bi){
      float d = dg32[((size_t)bi*16 + l)*31 + m];
      cplx v = what0[((size_t)oi*2 + bi)*31 + m];
      sx += d*v.x; sy += d*v.y;
    }
  }
  Psi0[idx] = make_float2(sx, sy);
}

__global__ void k_Z0(const cplx* __restrict__ X0, const cplx* __restrict__ Psi0, cplx* __restrict__ Z){
  int idx = blockIdx.x*blockDim.x + threadIdx.x;
  if(idx >= 8*32*16*961) return;
  int q = idx % 31;
  int p = (idx/31) % 31;
  int l = (idx/961) % 16;
  int o = (idx/(961*16)) % 32;
  int c = idx/(961*16*32);
  float sx = 0.f, sy = 0.f;
  if(iabs_(p-15) <= l && iabs_(q-15) <= l){
    for(int i = 0; i < 3; ++i){
      cplx a = X0[(((size_t)c*3 + i)*16 + l)*31 + p];
      cplx b = Psi0[(((size_t)o*3 + i)*16 + l)*31 + q];
      sx += a.x*b.x + a.y*b.y;
      sy += a.y*b.x - a.x*b.y;
    }
  }
  Z[idx] = make_float2(sx, sy);
}

// ============ j-batched SO3 inverse FFT, Hermitian-halved, j-packed W ============
template<int JB, int STAT>
__global__ void k_ifft_b2(const cplx* __restrict__ Zt, const float* __restrict__ Wst,
                          const cplx* __restrict__ E, float* __restrict__ out,
                          float2* __restrict__ part, int b){
  int M = 2*b-1, n2 = 2*b, Mp = n2, cw = b-1;
  int hg = b/4;
  int gc = n2/4;
  int Tst = b+1;
  int MM = M*M, HH = (MM+1)/2;
  extern __shared__ char smem[];
  cplx* Es = (cplx*)smem;
  cplx* gt = Es + M*n2;
  __shared__ float2 redw[16];
  int nj = n2/JB;
  int j0 = (blockIdx.x % nj)*JB;
  int co = blockIdx.x / nj;
  int tid = threadIdx.x, bd = blockDim.x;
  for(int t = tid; t < M*n2; t += bd) Es[t] = E[t];
  const cplx* Zp = Zt + (size_t)co*b*MM;
  const float4* W4 = (const float4*)Wst;   // packed [j/4][l][MM][4]
  int jg0 = j0 >> 2;
  float a1 = 0.f, a2c = 0.f;
  for(int t = tid; t < HH; t += bd){
    int p = t/M, q = t - p*M;
    int lmin = iabs_(p-cw); int l2 = iabs_(q-cw); if(l2 > lmin) lmin = l2;
    float sx[JB], sy[JB];
    #pragma unroll
    for(int s = 0; s < JB; ++s){ sx[s] = 0.f; sy[s] = 0.f; }
    for(int l = lmin; l < b; ++l){
      cplx z = Zp[(size_t)l*MM + t];
      #pragma unroll
      for(int g = 0; g < JB/4; ++g){
        float4 w = W4[((size_t)((jg0+g)*b + l))*MM + t];
        sx[4*g+0] += w.x*z.x; sy[4*g+0] += w.x*z.y;
        sx[4*g+1] += w.y*z.x; sy[4*g+1] += w.y*z.y;
        sx[4*g+2] += w.z*z.x; sy[4*g+2] += w.z*z.y;
        sx[4*g+3] += w.w*z.x; sy[4*g+3] += w.w*z.y;
      }
    }
    int pm = M-1-p, qm = M-1-q;
    bool ism = (t < HH-1);
    float wgt = ism ? 2.f : 1.f;
    #pragma unroll
    for(int s = 0; s < JB; ++s){
      gt[s*M*Mp + p*Mp + q] = make_float2(sx[s], sy[s]);
      if(ism) gt[s*M*Mp + pm*Mp + qm] = make_float2(sx[s], -sy[s]);
      if(STAT){
        a2c += wgt*(sx[s]*sx[s] + sy[s]*sy[s]);
        if(!ism) a1 += sx[s];
      }
    }
  }
  if(STAT){
    for(int o = 32; o > 0; o >>= 1){ a1 += __shfl_down(a1, o); a2c += __shfl_down(a2c, o); }
    if((tid & 63) == 0) redw[tid>>6] = make_float2(a1, a2c);
  }
  __syncthreads();
  int tpj = b*gc;
  int slab = tid / tpj, tl = tid - slab*tpj;
  int a2i = tl/hg, dg = tl - a2i*hg; int d0 = 4*dg;
  float Tx[4]={0,0,0,0}, Ty[4]={0,0,0,0};
  {
    const cplx* gts = gt + slab*M*Mp;
    for(int p = 0; p < M; ++p){
      cplx e = Es[p*n2 + a2i];
      const cplx* gr = gts + p*Mp + cw + d0;
      #pragma unroll
      for(int u = 0; u < 4; ++u){
        cplx g = gr[u];
        Tx[u] += g.x*e.x - g.y*e.y;
        Ty[u] += g.x*e.y + g.y*e.x;
      }
    }
  }
  __syncthreads();
  if(STAT && tid == 0){
    float s1 = 0.f, s2 = 0.f;
    int nw = bd >> 6;
    for(int w = 0; w < nw; ++w){ s1 += redw[w].x; s2 += redw[w].y; }
    part[blockIdx.x] = make_float2(s1, s2);
  }
  {
    cplx* Tts = gt + slab*M*Mp;
    #pragma unroll
    for(int u = 0; u < 4; ++u)
      Tts[a2i*Tst + d0+u] = make_float2(Tx[u], Ty[u]);
  }
  __syncthreads();
  {
    int a = tl/gc, gg = tl - a*gc; int g0 = 4*gg;
    const cplx* T0 = gt + slab*M*Mp + a*Tst;
    const cplx* T1 = gt + slab*M*Mp + (a+b)*Tst;
    float t00 = T0[0].x, t10 = T1[0].x;
    float S0[4] = {t00,t00,t00,t00}, S1[4] = {t10,t10,t10,t10};
    for(int d = 1; d < b; ++d){
      const float4* e4 = (const float4*)(Es + (cw+d)*n2 + g0);
      float4 ea = e4[0], eb = e4[1];
      cplx t0 = T0[d], t1 = T1[d];
      float t0x = 2.f*t0.x, t0y = 2.f*t0.y, t1x = 2.f*t1.x, t1y = 2.f*t1.y;
      S0[0] += t0x*ea.x - t0y*ea.y;
      S0[1] += t0x*ea.z - t0y*ea.w;
      S0[2] += t0x*eb.x - t0y*eb.y;
      S0[3] += t0x*eb.z - t0y*eb.w;
      S1[0] += t1x*ea.x - t1y*ea.y;
      S1[1] += t1x*ea.z - t1y*ea.w;
      S1[2] += t1x*eb.x - t1y*eb.y;
      S1[3] += t1x*eb.z - t1y*eb.w;
    }
    float* op0 = out + (size_t)co*n2*n2*n2 + (size_t)(j0+slab)*n2*n2 + a*n2 + g0;
    float* op1 = op0 + (size_t)b*n2;
    *(float4*)op0 = make_float4(S0[0],S0[1],S0[2],S0[3]);
    *(float4*)op1 = make_float4(S1[0],S1[1],S1[2],S1[3]);
  }
}

// small (b=4) ifft + optional fused Parseval stats; Wst j-packed
__global__ void k_ifft_s(const cplx* __restrict__ Zt, const float* __restrict__ Wst,
                         const cplx* __restrict__ E, float* __restrict__ out,
                         float2* __restrict__ part, int stat, int b){
  int M = 2*b-1, n2 = 2*b, cw = b-1;
  int MM = M*M;
  extern __shared__ char smem[];
  cplx* gt = (cplx*)smem;
  cplx* Tt = gt + M*M;
  int blk = blockIdx.x;
  int j = blk % n2;
  int co = blk / n2;
  int jg = j >> 2, js = j & 3;
  const cplx* Zp = Zt + (size_t)co * b * M * M;
  for(int t = threadIdx.x; t < M*M; t += blockDim.x){
    int p = t / M, q = t % M;
    int lmin = iabs_(p-cw); int l2 = iabs_(q-cw); if(l2 > lmin) lmin = l2;
    float sx = 0.f, sy = 0.f;
    for(int l = lmin; l < b; ++l){
      float w = Wst[(((size_t)(jg*b + l))*MM + t)*4 + js];
      cplx z = Zp[((size_t)l*M + p)*M + q];
      sx += w*z.x; sy += w*z.y;
    }
    gt[t] = make_float2(sx, sy);
  }
  __syncthreads();
  if(stat){
    int center = (MM-1)/2;
    float a1 = 0.f, a2 = 0.f;
    for(int t = threadIdx.x; t < MM; t += blockDim.x){
      cplx g = gt[t];
      cplx m = gt[MM-1-t];
      float hx = 0.5f*(g.x + m.x);
      float hy = 0.5f*(g.y - m.y);
      a2 += hx*hx + hy*hy;
      if(t == center) a1 += g.x;
    }
    for(int o = 32; o > 0; o >>= 1){ a1 += __shfl_down(a1, o); a2 += __shfl_down(a2, o); }
    if(threadIdx.x == 0) part[blockIdx.x] = make_float2(a1, a2);
  }
  for(int t = threadIdx.x; t < n2*M; t += blockDim.x){
    int a = t / M, q = t % M;
    float sx = 0.f, sy = 0.f;
    for(int p = 0; p < M; ++p){
      cplx e = E[p*n2 + a];
      cplx g = gt[p*M + q];
      sx += g.x*e.x - g.y*e.y;
      sy += g.x*e.y + g.y*e.x;
    }
    Tt[t] = make_float2(sx, sy);
  }
  __syncthreads();
  float* op = out + (size_t)co*n2*n2*n2 + (size_t)j*n2*n2;
  for(int t = threadIdx.x; t < n2*n2; t += blockDim.x){
    int a = t / n2, g = t % n2;
    float s = 0.f;
    for(int q = 0; q < M; ++q){
      cplx e = E[q*n2 + g];
      cplx T = Tt[a*M + q];
      s += T.x*e.x - T.y*e.y;
    }
    op[t] = s;
  }
}

// ===== gstat: Hermitian-halved, register-only, j-packed W =====
template<int JB>
__global__ void k_gstat(const cplx* __restrict__ Zt, const float* __restrict__ Wst,
                        float2* __restrict__ part, int b){
  int M = 2*b-1, n2 = 2*b, cw = b-1;
  int MM = M*M, HH = (MM+1)/2;
  __shared__ float2 red[256];
  int nj = n2/JB;
  int j0 = (blockIdx.x % nj)*JB;
  int co = blockIdx.x / nj;
  int tid = threadIdx.x, bd = blockDim.x;
  const cplx* Zp = Zt + (size_t)co*b*MM;
  const float4* W4 = (const float4*)Wst;
  int jg0 = j0 >> 2;
  float a1 = 0.f, a2 = 0.f;
  for(int t = tid; t < HH; t += bd){
    int p = t/M, q = t - p*M;
    int lmin = iabs_(p-cw); int l2 = iabs_(q-cw); if(l2 > lmin) lmin = l2;
    float sx[JB], sy[JB];
    #pragma unroll
    for(int s = 0; s < JB; ++s){ sx[s] = 0.f; sy[s] = 0.f; }
    for(int l = lmin; l < b; ++l){
      cplx z = Zp[(size_t)l*MM + t];
      #pragma unroll
      for(int g = 0; g < JB/4; ++g){
        float4 w = W4[((size_t)((jg0+g)*b + l))*MM + t];
        sx[4*g+0] += w.x*z.x; sy[4*g+0] += w.x*z.y;
        sx[4*g+1] += w.y*z.x; sy[4*g+1] += w.y*z.y;
        sx[4*g+2] += w.z*z.x; sy[4*g+2] += w.z*z.y;
        sx[4*g+3] += w.w*z.x; sy[4*g+3] += w.w*z.y;
      }
    }
    float wgt = (t < HH-1) ? 2.f : 1.f;
    #pragma unroll
    for(int s = 0; s < JB; ++s){
      a2 += wgt*(sx[s]*sx[s] + sy[s]*sy[s]);
      if(t == HH-1) a1 += sx[s];
    }
  }
  red[tid] = make_float2(a1, a2);
  __syncthreads();
  for(int o = 128; o > 0; o >>= 1){
    if(tid < o){ red[tid].x += red[tid+o].x; red[tid].y += red[tid+o].y; }
    __syncthreads();
  }
  if(tid == 0) part[blockIdx.x] = red[0];
}

// GN-style finalize
__global__ void k_gstat_fin(const float2* __restrict__ part, float2* __restrict__ st,
                            int N, int Cch, int G, int nj, float denom_inv){
  int gi = threadIdx.x;
  if(gi >= N*G) return;
  int n = gi/G, grp = gi - n*G;
  int cpg = Cch/G;
  double s1 = 0.0, s2 = 0.0;
  for(int cc = 0; cc < cpg; ++cc){
    int co = n*Cch + grp*cpg + cc;
    for(int jg = 0; jg < nj; ++jg){
      float2 v = part[co*nj + jg];
      s1 += v.x; s2 += v.y;
    }
  }
  double mu = s1*denom_inv;
  double e2 = s2*denom_inv;
  st[gi] = make_float2((float)mu, (float)(1.0/sqrt(e2 - mu*mu + 1e-5)));
}

// BN-style finalize
__global__ void k_gstat_finB(const float2* __restrict__ part, float2* __restrict__ st,
                             int N, int C, int nj, float denom_inv){
  int c = threadIdx.x;
  if(c >= C) return;
  double s1 = 0.0, s2 = 0.0;
  for(int n = 0; n < N; ++n)
    for(int jg = 0; jg < nj; ++jg){
      float2 v = part[(n*C + c)*nj + jg];
      s1 += v.x; s2 += v.y;
    }
  double mu = s1*denom_inv;
  double e2 = s2*denom_inv;
  st[c] = make_float2((float)mu, (float)(1.0/sqrt(e2 - mu*mu + 1e-5)));
}

// ===== k_xk: fused ifft->GN(affine)->fft2->Xstep via K tables =====
__global__ void k_xk(const cplx* __restrict__ Z, const float* __restrict__ K,
                     const float* __restrict__ KB, const float* __restrict__ WxDC,
                     const float2* __restrict__ st, const float* __restrict__ gam,
                     const float* __restrict__ bet, cplx* __restrict__ X,
                     int CI, int Cch, int G, int Lout, int Lz, int Mt, int M, int off){
  int MtMt = Mt*Mt;
  int total = CI*MtMt;
  int idx = blockIdx.x*blockDim.x + threadIdx.x;
  if(idx >= total) return;
  int pq = idx % MtMt;
  int ci = idx/MtMt;
  int p = pq/Mt, q = pq - p*Mt;
  int cwt = (Mt-1)/2;
  int dp = iabs_(p-cwt), dq = iabs_(q-cwt);
  int lmin = dp > dq ? dp : dq;
  int n = ci/Cch, c = ci - n*Cch;
  int cpg = Cch/G;
  float2 sv = st[n*G + c/cpg];
  float sc = sv.y*gam[c];
  float tc = bet[c] - sv.x*sc;
  int pg = p + off, qg = q + off;
  const cplx* Za = Z + (size_t)ci*Lz*M*M + (size_t)pg*M + qg;
  const cplx* Zb = Z + (size_t)ci*Lz*M*M + (size_t)(M-1-pg)*M + (M-1-qg);
  for(int l = 0; l < Lout; ++l){
    cplx o = make_float2(0.f, 0.f);
    if(l >= lmin){
      float Ax=0.f, Ay=0.f, Bx=0.f, By=0.f;
      const float* Kl = K + ((size_t)l*Lz)*MtMt + pq;
      const float* KBl = KB + ((size_t)l*Lz)*MtMt + pq;
      for(int lp = lmin; lp < Lz; ++lp){
        float k = Kl[(size_t)lp*MtMt];
        float kb = KBl[(size_t)lp*MtMt];
        cplx za = Za[(size_t)lp*M*M];
        cplx zb = Zb[(size_t)lp*M*M];
        Ax += k*za.x; Ay += k*za.y;
        Bx += kb*zb.x; By += kb*zb.y;
      }
      o.x = 0.5f*sc*(Ax + Bx);
      o.y = 0.5f*sc*(Ay - By);
      if(dp == 0 && dq == 0) o.x += tc*WxDC[l];
    }
    X[((size_t)(ci*Lout + l)*Mt + p)*Mt + q] = o;
  }
}

// ======================= batched forward 2D DFT, Hermitian-halved =======================
// Both stages use full-slab lane compaction: 2 outputs/thread, zero masked lanes.
__global__ void k_fft2_b(const float* __restrict__ f, cplx* __restrict__ hf,
                         const cplx* __restrict__ E, int b, int Mt, int JB,
                         const float2* __restrict__ st, const float* __restrict__ gam,
                         const float* __restrict__ bet, int Cch, int cpg, int relu,
                         const float* __restrict__ f2, const float2* __restrict__ bst,
                         const float* __restrict__ bga, const float* __restrict__ bbe){
  int M = 2*b-1, n2 = 2*b;
  int off = (M - Mt)/2;
  int ng = (Mt+3)/4, MtP = 4*ng;
  int cwt = (Mt-1)/2;
  int dh = (Mt+1)/2;
  int hg2 = dh/2;
  int ngB = MtP/2;
  int fs = n2+1, es = n2+1;
  int tpj = n2*hg2;
  extern __shared__ char smem[];
  float* ft = (float*)smem;
  cplx* Ft  = (cplx*)(ft + JB*n2*fs);
  cplx* EsT = Ft + (size_t)JB*n2*MtP;
  cplx* Es  = EsT + (size_t)n2*dh;
  int nj = n2/JB;
  int ci = blockIdx.x / nj, jg = blockIdx.x % nj;
  int tid = threadIdx.x, bd = blockDim.x;
  float mu = 0.f, inv = 1.f, ga = 1.f, be = 0.f;
  float bmu = 0.f, binv = 1.f, bga_ = 1.f, bbe_ = 0.f;
  if(st){
    int c = ci % Cch, n = ci / Cch;
    float2 sv = st[n*(Cch/cpg) + c/cpg];
    mu = sv.x; inv = sv.y; ga = gam[c]; be = bet[c];
  }
  if(f2){
    int c = ci % Cch;
    float2 bv = bst[c];
    bmu = bv.x; binv = bv.y; bga_ = bga[c]; bbe_ = bbe[c];
  }
  const float* fbase = f + ((size_t)ci*n2 + (size_t)jg*JB)*n2*n2;
  const float* f2base = f2 ? (f2 + ((size_t)ci*n2 + (size_t)jg*JB)*n2*n2) : nullptr;
  for(int t = tid; t < JB*n2*n2; t += bd){
    int sj = t/(n2*n2); int r = t - sj*n2*n2;
    float v = fbase[(size_t)sj*n2*n2 + r];
    if(st){ v = (v - mu)*inv*ga + be; if(relu) v = fmaxf(v, 0.f); }
    if(f2){
      float vb = (f2base[(size_t)sj*n2*n2 + r] - bmu)*binv*bga_ + bbe_;
      v = fmaxf(v + vb, 0.f);
    }
    ft[sj*n2*fs + (r/n2)*fs + (r%n2)] = v;
  }
  for(int t = tid; t < n2*dh; t += bd){
    int g = t/dh, d = t - g*dh;
    EsT[t] = E[(cwt+d+off)*n2 + g];
  }
  for(int t = tid; t < Mt*n2; t += bd){
    int r = t/n2, a = t - r*n2;
    Es[r*es + a] = E[(r+off)*n2 + a];
  }
  __syncthreads();
  int slab = tid / tpj, tl = tid - slab*tpj;
  {
    int a = tl/hg2, dg = tl - a*hg2;
    int d0 = 2*dg;
    const float* fr = ft + slab*n2*fs + a*fs;
    float ax0=0.f, ax1=0.f, ay0=0.f, ay1=0.f;
    for(int g = 0; g < n2; ++g){
      float v = fr[g];
      const float4* e4 = (const float4*)(EsT + g*dh + d0);
      float4 ea = e4[0];
      ax0 += v*ea.x; ay0 -= v*ea.y;
      ax1 += v*ea.z; ay1 -= v*ea.w;
    }
    cplx* Fp = Ft + slab*n2*MtP + a*MtP;
    float vx[2] = {ax0, ax1};
    float vy[2] = {ay0, ay1};
    #pragma unroll
    for(int u = 0; u < 2; ++u){
      int d = d0+u;
      Fp[cwt+d] = make_float2(vx[u], vy[u]);
      if(d > 0) Fp[cwt-d] = make_float2(vx[u], -vy[u]);
    }
  }
  __syncthreads();
  {
    int ph = tl/ngB, qg = tl - ph*ngB; int q0 = 2*qg;
    int p = cwt + ph;
    float ax0=0.f, ax1=0.f, ay0=0.f, ay1=0.f;
    const cplx* Fb = Ft + slab*n2*MtP;
    for(int a = 0; a < n2; ++a){
      cplx e = Es[p*es + a];
      const float4* F4 = (const float4*)(Fb + a*MtP + q0);
      float4 Fa = F4[0];
      ax0 += e.x*Fa.x + e.y*Fa.y;  ay0 += e.x*Fa.y - e.y*Fa.x;
      ax1 += e.x*Fa.z + e.y*Fa.w;  ay1 += e.x*Fa.w - e.y*Fa.z;
    }
    float invn = 1.0f/((float)n2*(float)n2);
    int j = jg*JB + slab;
    cplx* hp = hf + ((size_t)ci*n2 + j)*Mt*Mt + p*Mt;
    cplx* hpm = hf + ((size_t)ci*n2 + j)*Mt*Mt + (cwt-ph)*Mt;
    float vx[2] = {ax0, ax1};
    float vy[2] = {ay0, ay1};
    #pragma unroll
    for(int u = 0; u < 2; ++u){
      int q = q0+u;
      if(q < Mt){
        hp[q] = make_float2(vx[u]*invn, vy[u]*invn);
        if(ph > 0) hpm[Mt-1-q] = make_float2(vx[u]*invn, -vy[u]*invn);
      }
    }
  }
}

// X Hermitian-halved + l-split
template<int LOUT>
__global__ void k_Xstep_h(const cplx* __restrict__ hf, const float* __restrict__ Wst,
                          cplx* __restrict__ X, int b, int Mt, int CI, int Ltot){
  int M = 2*b-1, n2 = 2*b, MM = M*M;
  int off = (M - Mt)/2, cw = (Mt-1)/2;
  int MtMt = Mt*Mt, HH = (MtMt+1)/2;
  int lbase = blockIdx.y*LOUT;
  int total = CI*HH;
  int idx = blockIdx.x*blockDim.x + threadIdx.x;
  if(idx >= total) return;
  int t = idx % HH;
  int ci = idx/HH;
  int p = t / Mt, q = t - p*Mt;
  int pm = Mt-1-p, qm = Mt-1-q;
  bool ism = (t < HH-1);
  float sgn = ((p + q) & 1) ? -1.f : 1.f;
  int dp = iabs_(p-cw), dq = iabs_(q-cw);
  int lmin = dp > dq ? dp : dq;
  float ax[LOUT], ay[LOUT];
  #pragma unroll
  for(int li = 0; li < LOUT; ++li){ ax[li] = 0.f; ay[li] = 0.f; }
  int wpq = (p+off)*M + (q+off);
  const cplx* hp = hf + (size_t)ci*n2*MtMt + (size_t)p*Mt + q;
  for(int j = 0; j < n2; ++j){
    cplx v = hp[(size_t)j*MtMt];
    const float* wj = Wst + ((size_t)j*b + lbase)*MM + wpq;
    #pragma unroll
    for(int li = 0; li < LOUT; ++li){
      if(lbase + li >= lmin){
        float w = wj[(size_t)li*MM];
        ax[li] += w*v.x; ay[li] += w*v.y;
      }
    }
  }
  cplx* xp = X + ((size_t)ci*Ltot + lbase)*MtMt;
  #pragma unroll
  for(int li = 0; li < LOUT; ++li){
    if(lbase + li >= lmin){
      xp[(size_t)li*MtMt + p*Mt + q] = make_float2(ax[li], ay[li]);
      if(ism) xp[(size_t)li*MtMt + pm*Mt + qm] = make_float2(sgn*ax[li], -sgn*ay[li]);
    }else{
      xp[(size_t)li*MtMt + p*Mt + q] = make_float2(0.f, 0.f);
      if(ism) xp[(size_t)li*MtMt + pm*Mt + qm] = make_float2(0.f, 0.f);
    }
  }
}

__global__ void k_what(const float* __restrict__ w, cplx* __restrict__ what,
                       const cplx* __restrict__ E, int n2, int Mt, int off, int OI){
  int total = OI*2*Mt;
  int idx = blockIdx.x*blockDim.x + threadIdx.x;
  if(idx >= total) return;
  int p = idx % Mt;
  int bi = (idx/Mt) & 1;
  int oi = idx/(2*Mt);
  const float* wr = w + (size_t)oi*4*n2 + (size_t)bi*2*n2;
  float sr = 0.f, si = 0.f;
  for(int a = 0; a < n2; ++a){
    float v = wr[2*a] + wr[2*a+1];
    cplx e = E[(p+off)*n2 + a];
    sr += v*e.x; si -= v*e.y;
  }
  what[idx] = make_float2(sr, si);
}

// ---- ystep: Hermitian-halved (pp,qq) grid, both bi in one thread ----
__global__ void k_ystep_h(const cplx* __restrict__ X, const float* __restrict__ Dg,
                          cplx* __restrict__ Y, int CI, int Wt, int Wd, int Lx, int Ld){
  int l = blockIdx.z;
  int K21 = 2*l+1;
  int KK = K21*K21, HH = (KK+1)/2;
  int cw = (Wt-1)/2, cwd = (Wd-1)/2;
  int l0 = cw - l, l0d = cwd - l;
  int tot = CI*HH;
  int idx = blockIdx.x*blockDim.x + threadIdx.x;
  if(idx >= tot) return;
  int t = idx % HH;
  int ci = idx/HH;
  int pp = t/K21, qq = t - pp*K21;
  int ppm = K21-1-pp, qqm = K21-1-qq;
  bool ism = (t < HH-1);
  float sgn = ((pp + qq) & 1) ? -1.f : 1.f;
  const cplx* xp = X + (((size_t)ci*Lx + l)*Wt + (pp+l0))*Wt + l0;
  const float* dp0 = Dg + (((size_t)0*Ld + l)*Wd + (qq+l0d))*Wd + l0d;
  const float* dp1 = Dg + (((size_t)1*Ld + l)*Wd + (qq+l0d))*Wd + l0d;
  float s0x=0.f, s0y=0.f, s1x=0.f, s1y=0.f;
  for(int k = 0; k < K21; ++k){
    cplx v = xp[k];
    float d0 = dp0[k], d1 = dp1[k];
    s0x += d0*v.x; s0y += d0*v.y;
    s1x += d1*v.x; s1y += d1*v.y;
  }
  size_t yoff = (size_t)CI*2*((size_t)l*(2*l-1)*(2*l+1)/3);
  cplx* yb = Y + yoff + (size_t)ci*K21*2*K21;
  yb[(pp*2+0)*K21 + qq] = make_float2(s0x, s0y);
  yb[(pp*2+1)*K21 + qq] = make_float2(s1x, s1y);
  if(ism){
    yb[(ppm*2+0)*K21 + qqm] = make_float2(sgn*s0x, -sgn*s0y);
    yb[(ppm*2+1)*K21 + qqm] = make_float2(sgn*s1x, -sgn*s1y);
  }
}

// Z via 2D (c,o) register tile, Hermitian-halved (p,q) grid with SIGNED conj mirror
template<int NC, int NO>
__global__ void k_zstep2(const cplx* __restrict__ Y, const cplx* __restrict__ what,
                         cplx* __restrict__ Z, int C, int O, int I, int Wt){
  int l = blockIdx.z;
  int Lz = gridDim.z;
  int K21 = 2*l+1;
  int cw = (Wt-1)/2;
  int l0 = cw - l;
  int WW = Wt*Wt, HH = (WW+1)/2;
  int Cg = C/NC, Og = O/NO;
  int tot = Cg*Og*HH;
  int idx = blockIdx.x*blockDim.x + threadIdx.x;
  if(idx >= tot) return;
  int t = idx % HH;
  int og = (idx/HH) % Og;
  int cg = idx/(HH*Og);
  int p = t / Wt, q = t - p*Wt;
  int pm = Wt-1-p, qm = Wt-1-q;
  bool ism = (t < HH-1);
  float sgn = ((p + q) & 1) ? -1.f : 1.f;
  int c0 = cg*NC, o0 = og*NO;
  bool valid = (iabs_(p-cw) <= l) && (iabs_(q-cw) <= l);
  if(!valid){
    cplx z0 = make_float2(0.f, 0.f);
    #pragma unroll
    for(int a = 0; a < NC; ++a)
      #pragma unroll
      for(int tt = 0; tt < NO; ++tt){
        size_t base = (((size_t)(c0+a)*O + (o0+tt))*Lz + l)*Wt;
        Z[(base + p)*Wt + q] = z0;
        if(ism) Z[(base + pm)*Wt + qm] = z0;
      }
    return;
  }
  int pp = p - l0, qq = q - l0;
  size_t yoff = (size_t)C*I*2*((size_t)l*(2*l-1)*(2*l+1)/3);
  const cplx* yb = Y + yoff + ((size_t)pp*2)*K21 + qq;
  size_t yci = (size_t)K21*2*K21;
  const cplx* wb = what + q;
  float ax[NC][NO], ay[NC][NO];
  #pragma unroll
  for(int a = 0; a < NC; ++a)
    #pragma unroll
    for(int tt = 0; tt < NO; ++tt){ ax[a][tt] = 0.f; ay[a][tt] = 0.f; }
  for(int i = 0; i < I; ++i){
    cplx y0[NC], y1[NC];
    #pragma unroll
    for(int a = 0; a < NC; ++a){
      const cplx* yp = yb + (size_t)((c0+a)*I + i)*yci;
      y0[a] = yp[0];
      y1[a] = yp[K21];
    }
    #pragma unroll
    for(int tt = 0; tt < NO; ++tt){
      size_t wo = (size_t)(((o0+tt)*I + i)*2)*Wt;
      cplx w0 = wb[wo];
      cplx w1 = wb[wo + Wt];
      #pragma unroll
      for(int a = 0; a < NC; ++a){
        ax[a][tt] += y0[a].x*w0.x + y0[a].y*w0.y + y1[a].x*w1.x + y1[a].y*w1.y;
        ay[a][tt] += y0[a].y*w0.x - y0[a].x*w0.y + y1[a].y*w1.x - y1[a].x*w1.y;
      }
    }
  }
  #pragma unroll
  for(int a = 0; a < NC; ++a)
    #pragma unroll
    for(int tt = 0; tt < NO; ++tt){
      size_t base = (((size_t)(c0+a)*O + (o0+tt))*Lz + l)*Wt;
      Z[(base + p)*Wt + q] = make_float2(ax[a][tt], ay[a][tt]);
      if(ism) Z[(base + pm)*Wt + qm] = make_float2(sgn*ax[a][tt], -sgn*ay[a][tt]);
    }
}

__global__ void k_zid(const cplx* __restrict__ X, const float* __restrict__ w,
                      cplx* __restrict__ Z, int C, int O, int I, int Lz, int Wt, int Wx, int Lx){
  int total = C*O*Lz*Wt*Wt;
  int idx = blockIdx.x*blockDim.x + threadIdx.x;
  if(idx >= total) return;
  int q = idx % Wt;
  int p = (idx/Wt) % Wt;
  int l = (idx/(Wt*Wt)) % Lz;
  int o = (idx/(Wt*Wt*Lz)) % O;
  int c = idx/(Wt*Wt*Lz*O);
  int cw = (Wt-1)/2, offx = (Wx-Wt)/2;
  float sx = 0.f, sy = 0.f;
  if(iabs_(p-cw) <= l && iabs_(q-cw) <= l){
    for(int i = 0; i < I; ++i){
      cplx v = X[((((size_t)c*I + i)*Lx + l)*Wx + p + offx)*Wx + q + offx];
      float wv = w[o*I + i];
      sx += wv*v.x; sy += wv*v.y;
    }
  }
  Z[idx] = make_float2(sx, sy);
}

// fused: out[n,c] = sum_jag relu( relu(gn(a)) + bn(b) ) * wq[j] / 64
__global__ void k_integrate2(const float* __restrict__ a, const float* __restrict__ bb,
                             const float2* __restrict__ gst, const float* __restrict__ gga,
                             const float* __restrict__ gbe,
                             const float2* __restrict__ bst, const float* __restrict__ bga,
                             const float* __restrict__ bbe,
                             const double* __restrict__ wq4, float* __restrict__ out,
                             int C, int G){
  int nc = blockIdx.x;
  int n = nc / C, c = nc % C;
  int cpg = C/G;
  float2 gs = gst[n*G + c/cpg];
  float2 bs = bst[c];
  float ga_ = gga[c], ge = gbe[c], ba = bga[c], be = bbe[c];
  const float* ap = a + (size_t)nc*512;
  const float* bp = bb + (size_t)nc*512;
  float s = 0.f;
  for(int t = threadIdx.x; t < 512; t += 64){
    int j = t >> 6;
    float va = fmaxf((ap[t]-gs.x)*gs.y*ga_ + ge, 0.f);
    float vb = (bp[t]-bs.x)*bs.y*ba + be;
    float h = fmaxf(va + vb, 0.f);
    s += h * (float)wq4[j];
  }
  for(int o = 32; o > 0; o >>= 1) s += __shfl_down(s, o);
  if(threadIdx.x == 0) out[nc] = s * (1.f/64.f);
}

// ======================= launch =======================
extern "C" void kernel_launch(void* const* d_in, const int* in_sizes, int n_in,
                              void* d_out, int out_size, void* d_ws, size_t ws_size,
                              hipStream_t stream){
  const float* xin = (const float*)d_in[0];
  const float* w0p = (const float*)d_in[1];
  const float* g0p = (const float*)d_in[2];
  const float* b0p = (const float*)d_in[3];
  const float* w1ap = (const float*)d_in[4];
  const float* g1ap = (const float*)d_in[5];
  const float* b1ap = (const float*)d_in[6];
  const float* w1bp = (const float*)d_in[7];
  const float* g1bp = (const float*)d_in[8];
  const float* b1bp = (const float*)d_in[9];
  const float* w1sp = (const float*)d_in[10];
  const float* g1sp = (const float*)d_in[11];
  const float* b1sp = (const float*)d_in[12];
  const float* w2ap = (const float*)d_in[13];
  const float* g2ap = (const float*)d_in[14];
  const float* b2ap = (const float*)d_in[15];
  const float* w2bp = (const float*)d_in[16];
  const float* g2bp = (const float*)d_in[17];
  const float* b2bp = (const float*)d_in[18];
  const float* w2sp = (const float*)d_in[19];
  const float* g2sp = (const float*)d_in[20];
  const float* b2sp = (const float*)d_in[21];
  float* outp = (float*)d_out;

  char* ws = (char*)d_ws;
  size_t off = 0;
  auto alloc = [&](size_t bytes)->char*{
    char* p = ws + off;
    off = (off + bytes + 255) & ~(size_t)255;
    return p;
  };
  // tables (persistent)
  double* lf   = (double*)alloc(130*8);
  double* wq   = (double*)alloc(120*8);
  cplx* E16    = (cplx*)alloc(31*32*8);
  cplx* E8     = (cplx*)alloc(15*16*8);
  cplx* E4     = (cplx*)alloc(7*8*8);
  cplx* E0f    = (cplx*)alloc(31*64*8);
  float* d032w = (float*)alloc((size_t)64*16*31*4);
  float* dg32  = (float*)alloc((size_t)2*16*31*4);
  float* Wi16  = (float*)alloc((size_t)32*16*961*4);
  float* Wx16  = (float*)alloc((size_t)32*16*961*4);
  float* Dg16  = (float*)alloc((size_t)2*16*961*4);
  float* Wi8   = (float*)alloc((size_t)16*8*225*4);
  float* Wx8   = (float*)alloc((size_t)16*8*225*4);
  float* Dg8   = (float*)alloc((size_t)2*8*225*4);
  float* Wi4   = (float*)alloc((size_t)8*4*49*4);
  // K tables
  float* K16   = (float*)alloc((size_t)8*16*225*4);
  float* KB16  = (float*)alloc((size_t)8*16*225*4);
  float* K8    = (float*)alloc((size_t)4*8*49*4);
  float* KB8   = (float*)alloc((size_t)4*8*49*4);
  float* WxDC16= (float*)alloc(8*4);
  float* WxDC8 = (float*)alloc(4*4);
  // stat partials
  float2* part_f = (float2*)alloc(8192*8);
  float2* st_h0 = (float2*)alloc(256*8);
  float2* st_l1 = (float2*)alloc(256*8);
  float2* st_l2 = (float2*)alloc(256*8);
  float2* st_s1 = (float2*)alloc(256*8);
  float2* st_l3 = (float2*)alloc(256*8);
  float2* st_l4 = (float2*)alloc(256*8);
  float2* st_s2 = (float2*)alloc(256*8);
  // arenas
  char* A_ZHF = alloc((size_t)63*1024*1024);
  char* A_X   = alloc((size_t)32*1024*1024);
  char* A_H1  = alloc((size_t)34*1024*1024);
  char* A_H2  = alloc((size_t)34*1024*1024);
  char* A_S   = alloc((size_t)8*1024*1024);

  // phase aliases
  cplx* xf0    = (cplx*)(A_S);
  cplx* X0     = (cplx*)(A_S + (512<<10));
  cplx* what0  = (cplx*)(A_S + (768<<10));
  cplx* Psi0   = (cplx*)(A_S + (1<<20));
  cplx* Zt0    = (cplx*)A_ZHF;
  float* h0    = (float*)A_H1;
  cplx* hf1    = (cplx*)A_ZHF;
  cplx* X1     = (cplx*)A_X;
  cplx* what1a = (cplx*)A_S;
  cplx* Y1a    = (cplx*)A_H2;
  cplx* Z1a    = (cplx*)A_ZHF;
  cplx* X1b    = (cplx*)A_S;
  cplx* what1b = (cplx*)(A_S + (4<<20));
  cplx* Y1b    = (cplx*)A_H1;
  cplx* Z1b    = (cplx*)A_ZHF;
  float* left2 = (float*)A_H1;
  cplx* Z1s    = (cplx*)A_ZHF;
  float* sc1   = (float*)(A_H1 + (12<<20));
  cplx* hf2    = (cplx*)A_ZHF;
  cplx* X2     = (cplx*)A_X;
  cplx* what2a = (cplx*)A_S;
  cplx* Y2a    = (cplx*)A_H2;
  cplx* Z2a    = (cplx*)A_ZHF;
  cplx* X2b    = (cplx*)A_S;
  cplx* what2b = (cplx*)(A_S + (1<<20));
  cplx* Y2b    = (cplx*)(A_S + (2<<20));
  cplx* Z2b    = (cplx*)A_ZHF;
  float* left4 = (float*)A_H1;
  cplx* Z2s    = (cplx*)A_ZHF;
  float* sc2   = (float*)(A_H1 + (4<<20));

  auto ifftb2_smem = [](int b, int JB)->size_t{
    int M = 2*b-1, n2 = 2*b;
    return (size_t)(M*n2 + JB*M*n2)*8;
  };
  auto fft2b_smem = [](int b, int Mt, int JB)->size_t{
    int n2 = 2*b; int ng = (Mt+3)/4, MtP = 4*ng;
    int dh = (Mt+1)/2;
    return (size_t)(JB*n2*(n2+1))*4 + (size_t)(JB*n2*MtP)*8
         + (size_t)(n2*dh)*8 + (size_t)(Mt*(n2+1))*8;
  };

  // ---- tables ----
  k_tables<<<1,256,0,stream>>>(lf, wq);
  k_twiddle<<<(31*32+255)/256,256,0,stream>>>(E16, 31, 32, 15,  1.0);
  k_twiddle<<<1,256,0,stream>>>(E8, 15, 16, 7,  1.0);
  k_twiddle<<<1,64,0,stream>>>(E4, 7, 8, 3,  1.0);
  k_twiddle<<<(31*64+255)/256,256,0,stream>>>(E0f, 31, 64, 15, -1.0);
  k_wigner_col0<<<(64*16*31+255)/256,256,0,stream>>>(lf, d032w, 64, 16, 31, 0, 32, wq, 2);
  k_wigner_col0<<<(2*16*31+255)/256,256,0,stream>>>(lf, dg32, 2, 16, 31, 1, 0, wq, 0);
  k_wigner_full2<<<(32*16*961+255)/256,256,0,stream>>>(lf, Wi16, Wx16, 32, 16, 31, 16, wq+64);
  k_wigner_full<<<(2*16*961+255)/256,256,0,stream>>>(lf, Dg16, 2, 16, 31, 1, 0, wq, 0, 0);
  k_wigner_full2<<<(16*8*225+255)/256,256,0,stream>>>(lf, Wi8, Wx8, 16, 8, 15, 8, wq+96);
  k_wigner_full<<<(2*8*225+255)/256,256,0,stream>>>(lf, Dg8, 2, 8, 15, 1, 0, wq, 0, 0);
  k_wigner_full<<<(8*4*49+255)/256,256,0,stream>>>(lf, Wi4, 8, 4, 7, 0, 4, wq, 1, 1);
  k_ktab<<<(8*16*225+255)/256,256,0,stream>>>(Wx16, Wi16, K16, KB16, 8, 16, 16, 15, 31, 8, 32);
  k_ktab<<<(4*8*49+255)/256,256,0,stream>>>(Wx8, Wi8, K8, KB8, 4, 8, 8, 7, 15, 4, 16);
  k_wxdc<<<1,64,0,stream>>>(Wx16, WxDC16, 8, 16, 31, 32);
  k_wxdc<<<1,64,0,stream>>>(Wx8, WxDC8, 4, 8, 15, 16);

  // ---- layer 0: s2_conv(x, w0, 32, 16); GN stats fused into ifft ----
  k_fft0<<<(1536*31+255)/256,256,0,stream>>>(xin, xf0, E0f);
  k_what0<<<(96*2*31+255)/256,256,0,stream>>>(w0p, E0f, what0);
  k_X0<<<(24*16*31+255)/256,256,0,stream>>>(xf0, d032w, X0);
  k_Psi0<<<(96*16*31+255)/256,256,0,stream>>>(what0, dg32, Psi0);
  k_Z0<<<(8*32*16*961+255)/256,256,0,stream>>>(X0, Psi0, Zt0);
  k_ifft_b2<4,1><<<8*32*8,512,ifftb2_smem(16,4),stream>>>(Zt0, Wi16, E16, h0, part_f, 16);
  k_gstat_fin<<<1,128,0,stream>>>(part_f, st_h0, 8, 32, 16, 8, 1.f/64.f);

  // ---- layer 1a: so3_conv(h, w1a, 16, 16) ----
  k_fft2_b<<<256*16,512,fft2b_smem(16,31,2),stream>>>(h0, hf1, E16, 16, 31, 2,
      st_h0, g0p, b0p, 32, 2, 1, nullptr, nullptr, nullptr, nullptr);
  { dim3 g((256*481+255)/256, 2);
    k_Xstep_h<8><<<g,256,0,stream>>>(hf1, Wx16, X1, 16, 31, 256, 16); }
  k_what<<<(1024*2*31+255)/256,256,0,stream>>>(w1ap, what1a, E16, 32, 31, 0, 1024);
  { dim3 g((256*481+255)/256,1,16);
    k_ystep_h<<<g,256,0,stream>>>(X1, Dg16, Y1a, 256, 31, 31, 16, 16); }
  { dim3 g((2*8*481+255)/256,1,16);
    k_zstep2<4,4><<<g,256,0,stream>>>(Y1a, what1a, Z1a, 8, 32, 32, 31); }
  k_gstat<8><<<256*4,256,0,stream>>>(Z1a, Wi16, part_f, 16);
  k_gstat_fin<<<1,128,0,stream>>>(part_f, st_l1, 8, 32, 16, 4, 1.f/64.f);
  k_xk<<<(256*225+255)/256,256,0,stream>>>(Z1a, K16, KB16, WxDC16,
                                           st_l1, g1ap, b1ap, X1b,
                                           256, 32, 16, 8, 16, 15, 31, 8);

  // ---- layer 1b: so3_conv(left, w1b, 16, 8); GN stats fused into ifft ----
  k_what<<<(2048*2*15+255)/256,256,0,stream>>>(w1bp, what1b, E16, 32, 15, 8, 2048);
  { dim3 g((256*113+255)/256,1,8);
    k_ystep_h<<<g,256,0,stream>>>(X1b, Dg16, Y1b, 256, 15, 31, 8, 16); }
  { dim3 g((4*16*113+255)/256,1,8);
    k_zstep2<2,4><<<g,256,0,stream>>>(Y1b, what1b, Z1b, 8, 64, 32, 15); }
  k_ifft_b2<16,1><<<8*64,512,ifftb2_smem(8,16),stream>>>(Z1b, Wi8, E8, left2, part_f, 8);
  k_gstat_fin<<<1,128,0,stream>>>(part_f, st_l2, 8, 64, 16, 1, 1.f/64.f);

  // ---- layer 1s: shortcut conv; BN stats fused into ifft ----
  k_zid<<<(8*64*8*225+255)/256,256,0,stream>>>(X1, w1sp, Z1s, 8, 64, 32, 8, 15, 31, 16);
  k_ifft_b2<16,1><<<8*64,512,ifftb2_smem(8,16),stream>>>(Z1s, Wi8, E8, sc1, part_f, 8);
  k_gstat_finB<<<1,128,0,stream>>>(part_f, st_s1, 8, 64, 1, 1.f/128.f);

  // ---- layer 2a: so3_conv(h, w2a, 8, 8); residual join fused into fft2 staging ----
  k_fft2_b<<<512*4,256,fft2b_smem(8,15,4),stream>>>(left2, hf2, E8, 8, 15, 4,
      st_l2, g1bp, b1bp, 64, 4, 1, sc1, st_s1, g1sp, b1sp);
  { dim3 g((512*113+255)/256, 2);
    k_Xstep_h<4><<<g,256,0,stream>>>(hf2, Wx8, X2, 8, 15, 512, 8); }
  k_what<<<(4096*2*15+255)/256,256,0,stream>>>(w2ap, what2a, E8, 16, 15, 0, 4096);
  { dim3 g((512*113+255)/256,1,8);
    k_ystep_h<<<g,256,0,stream>>>(X2, Dg8, Y2a, 512, 15, 15, 8, 8); }
  { dim3 g((4*16*113+255)/256,1,8);
    k_zstep2<2,4><<<g,256,0,stream>>>(Y2a, what2a, Z2a, 8, 64, 64, 15); }
  k_gstat<16><<<512,256,0,stream>>>(Z2a, Wi8, part_f, 8);
  k_gstat_fin<<<1,128,0,stream>>>(part_f, st_l3, 8, 64, 16, 1, 1.f/64.f);
  k_xk<<<(512*49+255)/256,256,0,stream>>>(Z2a, K8, KB8, WxDC8,
                                          st_l3, g2ap, b2ap, X2b,
                                          512, 64, 16, 4, 8, 7, 15, 4);

  // ---- layer 2b: so3_conv(left, w2b, 8, 4); GN stats fused into ifft ----
  k_what<<<(8192*2*7+255)/256,256,0,stream>>>(w2bp, what2b, E8, 16, 7, 4, 8192);
  { dim3 g((512*25+255)/256,1,4);
    k_ystep_h<<<g,256,0,stream>>>(X2b, Dg8, Y2b, 512, 7, 15, 4, 8); }
  { dim3 g((8*64*25+255)/256,1,4);
    k_zstep2<1,2><<<g,256,0,stream>>>(Y2b, what2b, Z2b, 8, 128, 64, 7); }
  k_ifft_s<<<8*128*8,64,(49+56)*8,stream>>>(Z2b, Wi4, E4, left4, part_f, 1, 4);
  k_gstat_fin<<<1,256,0,stream>>>(part_f, st_l4, 8, 128, 32, 8, 1.f/32.f);

  // ---- layer 2s: shortcut conv; BN stats fused into ifft ----
  k_zid<<<(8*128*4*49+255)/256,256,0,stream>>>(X2, w2sp, Z2s, 8, 128, 64, 4, 7, 15, 8);
  k_ifft_s<<<8*128*8,64,(49+56)*8,stream>>>(Z2s, Wi4, E4, sc2, part_f, 1, 4);
  k_gstat_finB<<<1,128,0,stream>>>(part_f, st_s2, 8, 128, 8, 1.f/64.f);

  // ---- fused residual join + integrate ----
  k_integrate2<<<1024,64,0,stream>>>(left4, sc2, st_l4, g2bp, b2bp,
                                     st_s2, g2sp, b2sp, wq+112, outp, 128, 32);
}

// Round 21
// 918.133 us; speedup vs baseline: 1.5638x; 1.0194x over previous
//
#include <hip/hip_runtime.h>
#include <math.h>

typedef float2 cplx;
#define PI_D 3.14159265358979323846

__device__ __forceinline__ int iabs_(int v){ return v < 0 ? -v : v; }

// ======================= table kernels =======================
__global__ void k_tables(double* lf, double* wq){
  if(threadIdx.x == 0){
    lf[0] = 0.0;
    double acc = 0.0;
    for(int i = 1; i <= 128; ++i){ acc += log((double)i); lf[i] = acc; }
  }
  int t = threadIdx.x;
  int b, j, off;
  if(t < 64){ b = 32; j = t; off = 0; }
  else if(t < 96){ b = 16; j = t - 64; off = 64; }
  else if(t < 112){ b = 8; j = t - 96; off = 96; }
  else if(t < 120){ b = 4; j = t - 112; off = 112; }
  else return;
  double beta = PI_D * (2*j+1) / (4.0*b);
  double s = 0.0;
  for(int p = 0; p < b; ++p) s += sin((2*p+1)*beta) / (2*p+1);
  wq[off+j] = 2.0*PI_D/((double)b*b) * sin(beta) * s;
}

__global__ void k_twiddle(cplx* E, int nfreq, int n, int center, double sgn){
  int idx = blockIdx.x*blockDim.x + threadIdx.x;
  if(idx >= nfreq*n) return;
  int p = idx / n, a = idx % n;
  double ang = sgn * 2.0*PI_D * (double)(p-center) * (double)a / (double)n;
  E[idx] = make_float2((float)cos(ang), (float)sin(ang));
}

// Wigner-d, n=0 column only; smode: 0 none, 1 *(2l+1), 2 *wqs[j]
__global__ void k_wigner_col0(const double* __restrict__ lf, float* __restrict__ out,
                              int nb, int Lmax, int W, int mode, int bq,
                              const double* __restrict__ wqs, int smode){
  int idx = blockIdx.x*blockDim.x + threadIdx.x;
  int total = nb*Lmax*W;
  if(idx >= total) return;
  int m = idx % W;
  int l = (idx/W) % Lmax;
  int j = idx/(W*Lmax);
  int cw = (W-1)/2;
  int mh = m - cw;
  float r = 0.f;
  if(iabs_(mh) <= l){
    double beta = (mode==0) ? PI_D*(2*j+1)/(4.0*bq) : PI_D*(j+1)/16.0;
    double cb = cos(0.5*beta), sb = sin(0.5*beta);
    double lcb = log(cb), lsb = log(sb);
    int k0 = (mh < 0) ? -mh : 0;
    int k1 = (mh > 0) ? (l - mh) : l;
    double s = 0.0;
    for(int k = k0; k <= k1; ++k){
      double logc = 0.5*(lf[l+mh] + lf[l-mh] + 2.0*lf[l])
                    - lf[l-k] - lf[k] - lf[mh+k] - lf[l-mh-k];
      double term = exp(logc + (double)(2*l - mh - 2*k)*lcb + (double)(mh + 2*k)*lsb);
      s += ((mh + k) & 1) ? -term : term;
    }
    if(smode == 1) s *= (double)(2*l+1);
    else if(smode == 2) s *= wqs[j];
    r = (float)s;
  }
  out[idx] = r;
}

// Full Wigner-d; smode: 0 none, 1 *(2l+1), 2 *wqs[j]
// pack!=0: write j-packed layout [j/4][l][W*W][4]
__global__ void k_wigner_full(const double* __restrict__ lf, float* __restrict__ out,
                              int nb, int L, int W, int mode, int bq,
                              const double* __restrict__ wqs, int smode, int pack){
  int idx = blockIdx.x*blockDim.x + threadIdx.x;
  int total = nb*L*W*W;
  if(idx >= total) return;
  int q = idx % W;
  int p = (idx/W) % W;
  int l = (idx/(W*W)) % L;
  int j = idx/(W*W*L);
  int cw = (W-1)/2;
  int mh = p - cw, nh = q - cw;
  float r = 0.f;
  if(iabs_(mh) <= l && iabs_(nh) <= l){
    double beta = (mode==0) ? PI_D*(2*j+1)/(4.0*bq) : PI_D*(j+1)/16.0;
    double cb = cos(0.5*beta), sb = sin(0.5*beta);
    double lcb = log(cb), lsb = log(sb);
    int k0 = (nh - mh > 0) ? (nh - mh) : 0;
    int a1 = l + nh, b1 = l - mh;
    int k1 = (a1 < b1) ? a1 : b1;
    double s = 0.0;
    for(int k = k0; k <= k1; ++k){
      double logc = 0.5*(lf[l+mh] + lf[l-mh] + lf[l+nh] + lf[l-nh])
                    - lf[l+nh-k] - lf[k] - lf[mh-nh+k] - lf[l-mh-k];
      double term = exp(logc + (double)(2*l + nh - mh - 2*k)*lcb + (double)(mh - nh + 2*k)*lsb);
      s += ((mh - nh + k) & 1) ? -term : term;
    }
    if(smode == 1) s *= (double)(2*l+1);
    else if(smode == 2) s *= wqs[j];
    r = (float)s;
  }
  if(pack)
    out[(((size_t)(j>>2)*L + l)*(W*W) + (p*W+q))*4 + (j&3)] = r;
  else
    out[idx] = r;
}

// Merged: computes the Wigner series ONCE.
// outA = d*(2l+1) in j-PACKED layout [j/4][l][W*W][4]; outB = d*wqs[j] normal layout.
__global__ void k_wigner_full2(const double* __restrict__ lf, float* __restrict__ outA,
                               float* __restrict__ outB, int nb, int L, int W, int bq,
                               const double* __restrict__ wqs){
  int idx = blockIdx.x*blockDim.x + threadIdx.x;
  int total = nb*L*W*W;
  if(idx >= total) return;
  int q = idx % W;
  int p = (idx/W) % W;
  int l = (idx/(W*W)) % L;
  int j = idx/(W*W*L);
  int cw = (W-1)/2;
  int mh = p - cw, nh = q - cw;
  double s = 0.0;
  if(iabs_(mh) <= l && iabs_(nh) <= l){
    double beta = PI_D*(2*j+1)/(4.0*bq);
    double cb = cos(0.5*beta), sb = sin(0.5*beta);
    double lcb = log(cb), lsb = log(sb);
    int k0 = (nh - mh > 0) ? (nh - mh) : 0;
    int a1 = l + nh, b1 = l - mh;
    int k1 = (a1 < b1) ? a1 : b1;
    for(int k = k0; k <= k1; ++k){
      double logc = 0.5*(lf[l+mh] + lf[l-mh] + lf[l+nh] + lf[l-nh])
                    - lf[l+nh-k] - lf[k] - lf[mh-nh+k] - lf[l-mh-k];
      double term = exp(logc + (double)(2*l + nh - mh - 2*k)*lcb + (double)(mh - nh + 2*k)*lsb);
      s += ((mh - nh + k) & 1) ? -term : term;
    }
  }
  outA[(((size_t)(j>>2)*L + l)*(W*W) + (p*W+q))*4 + (j&3)] = (float)(s*(double)(2*l+1));
  outB[idx] = (float)(s*wqs[j]);
}

// K tables for fused GN->conv links; Wi is j-PACKED [j/4][Lfull][M*M][4], Wx normal
__global__ void k_ktab(const float* __restrict__ Wx, const float* __restrict__ Wi,
                       float* __restrict__ K, float* __restrict__ KB,
                       int Lout, int Lz, int Lfull, int Mt, int M, int off, int nj){
  int MtMt = Mt*Mt;
  int MM = M*M;
  int total = Lout*Lz*MtMt;
  int idx = blockIdx.x*blockDim.x + threadIdx.x;
  if(idx >= total) return;
  int pq = idx % MtMt;
  int lp = (idx/MtMt) % Lz;
  int l = idx/(MtMt*Lz);
  int p = pq/Mt, q = pq - p*Mt;
  int pg = p + off, qg = q + off;
  float sA = 0.f, sB = 0.f;
  for(int j = 0; j < nj; ++j){
    float wx = Wx[(((size_t)j*Lfull + l)*M + pg)*M + qg];
    sA += wx * Wi[(((size_t)(j>>2)*Lfull + lp)*MM + (pg*M + qg))*4 + (j&3)];
    sB += wx * Wi[(((size_t)(j>>2)*Lfull + lp)*MM + ((M-1-pg)*M + (M-1-qg)))*4 + (j&3)];
  }
  K[idx] = sA;
  KB[idx] = sB;
}

__global__ void k_wxdc(const float* __restrict__ Wx, float* __restrict__ dc,
                       int Lout, int Lfull, int M, int nj){
  int l = threadIdx.x;
  if(l >= Lout) return;
  int c0 = (M-1)/2;
  float s = 0.f;
  for(int j = 0; j < nj; ++j)
    s += Wx[(((size_t)j*Lfull + l)*M + c0)*M + c0];
  dc[l] = s;
}

// ======================= layer-0 (S2) kernels =======================
__global__ void k_fft0(const float* __restrict__ x, cplx* __restrict__ xf, const cplx* __restrict__ E0f){
  int idx = blockIdx.x*blockDim.x + threadIdx.x;
  if(idx >= 1536*31) return;
  int m = idx % 31;
  int r = idx / 31;
  const float* xr = x + (size_t)r*64;
  float sr = 0.f, si = 0.f;
  for(int a = 0; a < 64; ++a){
    cplx e = E0f[m*64 + a];
    float v = xr[a];
    sr += v*e.x; si += v*e.y;
  }
  xf[idx] = make_float2(sr*(1.f/64.f), si*(1.f/64.f));
}

__global__ void k_what0(const float* __restrict__ w0, const cplx* __restrict__ E0f, cplx* __restrict__ what0){
  int idx = blockIdx.x*blockDim.x + threadIdx.x;
  if(idx >= 96*2*31) return;
  int m = idx % 31;
  int bi = (idx/31) & 1;
  int oi = idx/62;
  const float* wr = w0 + (size_t)oi*128 + bi*64;
  float sr = 0.f, si = 0.f;
  for(int a = 0; a < 64; ++a){
    cplx e = E0f[m*64 + a];
    float v = wr[a];
    sr += v*e.x; si += v*e.y;
  }
  what0[idx] = make_float2(sr, si);
}

__global__ void k_X0(const cplx* __restrict__ xf, const float* __restrict__ d032w,
                     cplx* __restrict__ X0){
  int idx = blockIdx.x*blockDim.x + threadIdx.x;
  if(idx >= 24*16*31) return;
  int m = idx % 31;
  int l = (idx/31) % 16;
  int ci = idx/(31*16);
  float sx = 0.f, sy = 0.f;
  if(iabs_(m-15) <= l){
    for(int j = 0; j < 64; ++j){
      float d = d032w[((size_t)j*16 + l)*31 + m];
      cplx v = xf[((size_t)ci*64 + j)*31 + m];
      sx += d*v.x; sy += d*v.y;
    }
  }
  X0[idx] = make_float2(sx, sy);
}

__global__ void k_Psi0(const cplx* __restrict__ what0, const float* __restrict__ dg32, cplx* __restrict__ Psi0){
  int idx = blockIdx.x*blockDim.x + threadIdx.x;
  if(idx >= 96*16*31) return;
  int m = idx % 31;
  int l = (idx/31) % 16;
  int oi = idx/(31*16);
  float sx = 0.f, sy = 0.f;
  if(iabs_(m-15) <= l){
    for(int bi = 0; bi < 2; ++bi){
      float d = dg32[((size_t)bi*16 + l)*31 + m];
      cplx v = what0[((size_t)oi*2 + bi)*31 + m];
      sx += d*v.x; sy += d*v.y;
    }
  }
  Psi0[idx] = make_float2(sx, sy);
}

__global__ void k_Z0(const cplx* __restrict__ X0, const cplx* __restrict__ Psi0, cplx* __restrict__ Z){
  int idx = blockIdx.x*blockDim.x + threadIdx.x;
  if(idx >= 8*32*16*961) return;
  int q = idx % 31;
  int p = (idx/31) % 31;
  int l = (idx/961) % 16;
  int o = (idx/(961*16)) % 32;
  int c = idx/(961*16*32);
  float sx = 0.f, sy = 0.f;
  if(iabs_(p-15) <= l && iabs_(q-15) <= l){
    for(int i = 0; i < 3; ++i){
      cplx a = X0[(((size_t)c*3 + i)*16 + l)*31 + p];
      cplx b = Psi0[(((size_t)o*3 + i)*16 + l)*31 + q];
      sx += a.x*b.x + a.y*b.y;
      sy += a.y*b.x - a.x*b.y;
    }
  }
  Z[idx] = make_float2(sx, sy);
}

// ============ j-batched SO3 inverse FFT, Hermitian-halved, j-packed W ============
template<int JB, int STAT>
__global__ void k_ifft_b2(const cplx* __restrict__ Zt, const float* __restrict__ Wst,
                          const cplx* __restrict__ E, float* __restrict__ out,
                          float2* __restrict__ part, int b){
  int M = 2*b-1, n2 = 2*b, Mp = n2, cw = b-1;
  int hg = b/4;
  int gc = n2/4;
  int Tst = b+1;
  int MM = M*M, HH = (MM+1)/2;
  extern __shared__ char smem[];
  cplx* Es = (cplx*)smem;
  cplx* gt = Es + M*n2;
  __shared__ float2 redw[16];
  int nj = n2/JB;
  int j0 = (blockIdx.x % nj)*JB;
  int co = blockIdx.x / nj;
  int tid = threadIdx.x, bd = blockDim.x;
  for(int t = tid; t < M*n2; t += bd) Es[t] = E[t];
  const cplx* Zp = Zt + (size_t)co*b*MM;
  const float4* W4 = (const float4*)Wst;   // packed [j/4][l][MM][4]
  int jg0 = j0 >> 2;
  float a1 = 0.f, a2c = 0.f;
  for(int t = tid; t < HH; t += bd){
    int p = t/M, q = t - p*M;
    int lmin = iabs_(p-cw); int l2 = iabs_(q-cw); if(l2 > lmin) lmin = l2;
    float sx[JB], sy[JB];
    #pragma unroll
    for(int s = 0; s < JB; ++s){ sx[s] = 0.f; sy[s] = 0.f; }
    for(int l = lmin; l < b; ++l){
      cplx z = Zp[(size_t)l*MM + t];
      #pragma unroll
      for(int g = 0; g < JB/4; ++g){
        float4 w = W4[((size_t)((jg0+g)*b + l))*MM + t];
        sx[4*g+0] += w.x*z.x; sy[4*g+0] += w.x*z.y;
        sx[4*g+1] += w.y*z.x; sy[4*g+1] += w.y*z.y;
        sx[4*g+2] += w.z*z.x; sy[4*g+2] += w.z*z.y;
        sx[4*g+3] += w.w*z.x; sy[4*g+3] += w.w*z.y;
      }
    }
    int pm = M-1-p, qm = M-1-q;
    bool ism = (t < HH-1);
    float wgt = ism ? 2.f : 1.f;
    #pragma unroll
    for(int s = 0; s < JB; ++s){
      gt[s*M*Mp + p*Mp + q] = make_float2(sx[s], sy[s]);
      if(ism) gt[s*M*Mp + pm*Mp + qm] = make_float2(sx[s], -sy[s]);
      if(STAT){
        a2c += wgt*(sx[s]*sx[s] + sy[s]*sy[s]);
        if(!ism) a1 += sx[s];
      }
    }
  }
  if(STAT){
    for(int o = 32; o > 0; o >>= 1){ a1 += __shfl_down(a1, o); a2c += __shfl_down(a2c, o); }
    if((tid & 63) == 0) redw[tid>>6] = make_float2(a1, a2c);
  }
  __syncthreads();
  int tpj = b*gc;
  int slab = tid / tpj, tl = tid - slab*tpj;
  int a2i = tl/hg, dg = tl - a2i*hg; int d0 = 4*dg;
  float Tx[4]={0,0,0,0}, Ty[4]={0,0,0,0};
  {
    const cplx* gts = gt + slab*M*Mp;
    for(int p = 0; p < M; ++p){
      cplx e = Es[p*n2 + a2i];
      const cplx* gr = gts + p*Mp + cw + d0;
      #pragma unroll
      for(int u = 0; u < 4; ++u){
        cplx g = gr[u];
        Tx[u] += g.x*e.x - g.y*e.y;
        Ty[u] += g.x*e.y + g.y*e.x;
      }
    }
  }
  __syncthreads();
  if(STAT && tid == 0){
    float s1 = 0.f, s2 = 0.f;
    int nw = bd >> 6;
    for(int w = 0; w < nw; ++w){ s1 += redw[w].x; s2 += redw[w].y; }
    part[blockIdx.x] = make_float2(s1, s2);
  }
  {
    cplx* Tts = gt + slab*M*Mp;
    #pragma unroll
    for(int u = 0; u < 4; ++u)
      Tts[a2i*Tst + d0+u] = make_float2(Tx[u], Ty[u]);
  }
  __syncthreads();
  {
    int a = tl/gc, gg = tl - a*gc; int g0 = 4*gg;
    const cplx* T0 = gt + slab*M*Mp + a*Tst;
    const cplx* T1 = gt + slab*M*Mp + (a+b)*Tst;
    float t00 = T0[0].x, t10 = T1[0].x;
    float S0[4] = {t00,t00,t00,t00}, S1[4] = {t10,t10,t10,t10};
    for(int d = 1; d < b; ++d){
      const float4* e4 = (const float4*)(Es + (cw+d)*n2 + g0);
      float4 ea = e4[0], eb = e4[1];
      cplx t0 = T0[d], t1 = T1[d];
      float t0x = 2.f*t0.x, t0y = 2.f*t0.y, t1x = 2.f*t1.x, t1y = 2.f*t1.y;
      S0[0] += t0x*ea.x - t0y*ea.y;
      S0[1] += t0x*ea.z - t0y*ea.w;
      S0[2] += t0x*eb.x - t0y*eb.y;
      S0[3] += t0x*eb.z - t0y*eb.w;
      S1[0] += t1x*ea.x - t1y*ea.y;
      S1[1] += t1x*ea.z - t1y*ea.w;
      S1[2] += t1x*eb.x - t1y*eb.y;
      S1[3] += t1x*eb.z - t1y*eb.w;
    }
    float* op0 = out + (size_t)co*n2*n2*n2 + (size_t)(j0+slab)*n2*n2 + a*n2 + g0;
    float* op1 = op0 + (size_t)b*n2;
    *(float4*)op0 = make_float4(S0[0],S0[1],S0[2],S0[3]);
    *(float4*)op1 = make_float4(S1[0],S1[1],S1[2],S1[3]);
  }
}

// small (b=4) ifft + optional fused Parseval stats; Wst j-packed
__global__ void k_ifft_s(const cplx* __restrict__ Zt, const float* __restrict__ Wst,
                         const cplx* __restrict__ E, float* __restrict__ out,
                         float2* __restrict__ part, int stat, int b){
  int M = 2*b-1, n2 = 2*b, cw = b-1;
  int MM = M*M;
  extern __shared__ char smem[];
  cplx* gt = (cplx*)smem;
  cplx* Tt = gt + M*M;
  int blk = blockIdx.x;
  int j = blk % n2;
  int co = blk / n2;
  int jg = j >> 2, js = j & 3;
  const cplx* Zp = Zt + (size_t)co * b * M * M;
  for(int t = threadIdx.x; t < M*M; t += blockDim.x){
    int p = t / M, q = t % M;
    int lmin = iabs_(p-cw); int l2 = iabs_(q-cw); if(l2 > lmin) lmin = l2;
    float sx = 0.f, sy = 0.f;
    for(int l = lmin; l < b; ++l){
      float w = Wst[(((size_t)(jg*b + l))*MM + t)*4 + js];
      cplx z = Zp[((size_t)l*M + p)*M + q];
      sx += w*z.x; sy += w*z.y;
    }
    gt[t] = make_float2(sx, sy);
  }
  __syncthreads();
  if(stat){
    int center = (MM-1)/2;
    float a1 = 0.f, a2 = 0.f;
    for(int t = threadIdx.x; t < MM; t += blockDim.x){
      cplx g = gt[t];
      cplx m = gt[MM-1-t];
      float hx = 0.5f*(g.x + m.x);
      float hy = 0.5f*(g.y - m.y);
      a2 += hx*hx + hy*hy;
      if(t == center) a1 += g.x;
    }
    for(int o = 32; o > 0; o >>= 1){ a1 += __shfl_down(a1, o); a2 += __shfl_down(a2, o); }
    if(threadIdx.x == 0) part[blockIdx.x] = make_float2(a1, a2);
  }
  for(int t = threadIdx.x; t < n2*M; t += blockDim.x){
    int a = t / M, q = t % M;
    float sx = 0.f, sy = 0.f;
    for(int p = 0; p < M; ++p){
      cplx e = E[p*n2 + a];
      cplx g = gt[p*M + q];
      sx += g.x*e.x - g.y*e.y;
      sy += g.x*e.y + g.y*e.x;
    }
    Tt[t] = make_float2(sx, sy);
  }
  __syncthreads();
  float* op = out + (size_t)co*n2*n2*n2 + (size_t)j*n2*n2;
  for(int t = threadIdx.x; t < n2*n2; t += blockDim.x){
    int a = t / n2, g = t % n2;
    float s = 0.f;
    for(int q = 0; q < M; ++q){
      cplx e = E[q*n2 + g];
      cplx T = Tt[a*M + q];
      s += T.x*e.x - T.y*e.y;
    }
    op[t] = s;
  }
}

// ===== gstat: Hermitian-halved, register-only, j-packed W =====
template<int JB>
__global__ void k_gstat(const cplx* __restrict__ Zt, const float* __restrict__ Wst,
                        float2* __restrict__ part, int b){
  int M = 2*b-1, n2 = 2*b, cw = b-1;
  int MM = M*M, HH = (MM+1)/2;
  __shared__ float2 red[256];
  int nj = n2/JB;
  int j0 = (blockIdx.x % nj)*JB;
  int co = blockIdx.x / nj;
  int tid = threadIdx.x, bd = blockDim.x;
  const cplx* Zp = Zt + (size_t)co*b*MM;
  const float4* W4 = (const float4*)Wst;
  int jg0 = j0 >> 2;
  float a1 = 0.f, a2 = 0.f;
  for(int t = tid; t < HH; t += bd){
    int p = t/M, q = t - p*M;
    int lmin = iabs_(p-cw); int l2 = iabs_(q-cw); if(l2 > lmin) lmin = l2;
    float sx[JB], sy[JB];
    #pragma unroll
    for(int s = 0; s < JB; ++s){ sx[s] = 0.f; sy[s] = 0.f; }
    for(int l = lmin; l < b; ++l){
      cplx z = Zp[(size_t)l*MM + t];
      #pragma unroll
      for(int g = 0; g < JB/4; ++g){
        float4 w = W4[((size_t)((jg0+g)*b + l))*MM + t];
        sx[4*g+0] += w.x*z.x; sy[4*g+0] += w.x*z.y;
        sx[4*g+1] += w.y*z.x; sy[4*g+1] += w.y*z.y;
        sx[4*g+2] += w.z*z.x; sy[4*g+2] += w.z*z.y;
        sx[4*g+3] += w.w*z.x; sy[4*g+3] += w.w*z.y;
      }
    }
    float wgt = (t < HH-1) ? 2.f : 1.f;
    #pragma unroll
    for(int s = 0; s < JB; ++s){
      a2 += wgt*(sx[s]*sx[s] + sy[s]*sy[s]);
      if(t == HH-1) a1 += sx[s];
    }
  }
  red[tid] = make_float2(a1, a2);
  __syncthreads();
  for(int o = 128; o > 0; o >>= 1){
    if(tid < o){ red[tid].x += red[tid+o].x; red[tid].y += red[tid+o].y; }
    __syncthreads();
  }
  if(tid == 0) part[blockIdx.x] = red[0];
}

// GN-style finalize
__global__ void k_gstat_fin(const float2* __restrict__ part, float2* __restrict__ st,
                            int N, int Cch, int G, int nj, float denom_inv){
  int gi = threadIdx.x;
  if(gi >= N*G) return;
  int n = gi/G, grp = gi - n*G;
  int cpg = Cch/G;
  double s1 = 0.0, s2 = 0.0;
  for(int cc = 0; cc < cpg; ++cc){
    int co = n*Cch + grp*cpg + cc;
    for(int jg = 0; jg < nj; ++jg){
      float2 v = part[co*nj + jg];
      s1 += v.x; s2 += v.y;
    }
  }
  double mu = s1*denom_inv;
  double e2 = s2*denom_inv;
  st[gi] = make_float2((float)mu, (float)(1.0/sqrt(e2 - mu*mu + 1e-5)));
}

// BN-style finalize
__global__ void k_gstat_finB(const float2* __restrict__ part, float2* __restrict__ st,
                             int N, int C, int nj, float denom_inv){
  int c = threadIdx.x;
  if(c >= C) return;
  double s1 = 0.0, s2 = 0.0;
  for(int n = 0; n < N; ++n)
    for(int jg = 0; jg < nj; ++jg){
      float2 v = part[(n*C + c)*nj + jg];
      s1 += v.x; s2 += v.y;
    }
  double mu = s1*denom_inv;
  double e2 = s2*denom_inv;
  st[c] = make_float2((float)mu, (float)(1.0/sqrt(e2 - mu*mu + 1e-5)));
}

// ===== k_xk: fused ifft->GN(affine)->fft2->Xstep via K tables =====
// Only rows p <= cwt are computed (downstream ystep reads rows <= cwt only).
__global__ void k_xk(const cplx* __restrict__ Z, const float* __restrict__ K,
                     const float* __restrict__ KB, const float* __restrict__ WxDC,
                     const float2* __restrict__ st, const float* __restrict__ gam,
                     const float* __restrict__ bet, cplx* __restrict__ X,
                     int CI, int Cch, int G, int Lout, int Lz, int Mt, int M, int off){
  int MtMt = Mt*Mt;
  int cwt = (Mt-1)/2;
  int HHr = (cwt+1)*Mt;
  int total = CI*HHr;
  int idx = blockIdx.x*blockDim.x + threadIdx.x;
  if(idx >= total) return;
  int pq = idx % HHr;
  int ci = idx/HHr;
  int p = pq/Mt, q = pq - p*Mt;
  int dp = iabs_(p-cwt), dq = iabs_(q-cwt);
  int lmin = dp > dq ? dp : dq;
  int n = ci/Cch, c = ci - n*Cch;
  int cpg = Cch/G;
  float2 sv = st[n*G + c/cpg];
  float sc = sv.y*gam[c];
  float tc = bet[c] - sv.x*sc;
  int pg = p + off, qg = q + off;
  const cplx* Za = Z + (size_t)ci*Lz*M*M + (size_t)pg*M + qg;
  const cplx* Zb = Z + (size_t)ci*Lz*M*M + (size_t)(M-1-pg)*M + (M-1-qg);
  for(int l = 0; l < Lout; ++l){
    cplx o = make_float2(0.f, 0.f);
    if(l >= lmin){
      float Ax=0.f, Ay=0.f, Bx=0.f, By=0.f;
      const float* Kl = K + ((size_t)l*Lz)*MtMt + pq;
      const float* KBl = KB + ((size_t)l*Lz)*MtMt + pq;
      for(int lp = lmin; lp < Lz; ++lp){
        float k = Kl[(size_t)lp*MtMt];
        float kb = KBl[(size_t)lp*MtMt];
        cplx za = Za[(size_t)lp*M*M];
        cplx zb = Zb[(size_t)lp*M*M];
        Ax += k*za.x; Ay += k*za.y;
        Bx += kb*zb.x; By += kb*zb.y;
      }
      o.x = 0.5f*sc*(Ax + Bx);
      o.y = 0.5f*sc*(Ay - By);
      if(dp == 0 && dq == 0) o.x += tc*WxDC[l];
    }
    X[((size_t)(ci*Lout + l)*Mt + p)*Mt + q] = o;
  }
}

// ======================= batched forward 2D DFT, Hermitian-halved =======================
// Full-slab lane compaction; hf stores only the lower half (+ center row) since
// Xstep_h reads rows p <= cwt only.
__global__ void k_fft2_b(const float* __restrict__ f, cplx* __restrict__ hf,
                         const cplx* __restrict__ E, int b, int Mt, int JB,
                         const float2* __restrict__ st, const float* __restrict__ gam,
                         const float* __restrict__ bet, int Cch, int cpg, int relu,
                         const float* __restrict__ f2, const float2* __restrict__ bst,
                         const float* __restrict__ bga, const float* __restrict__ bbe){
  int M = 2*b-1, n2 = 2*b;
  int off = (M - Mt)/2;
  int ng = (Mt+3)/4, MtP = 4*ng;
  int cwt = (Mt-1)/2;
  int dh = (Mt+1)/2;
  int hg2 = dh/2;
  int ngB = MtP/2;
  int fs = n2+1, es = n2+1;
  int tpj = n2*hg2;
  extern __shared__ char smem[];
  float* ft = (float*)smem;
  cplx* Ft  = (cplx*)(ft + JB*n2*fs);
  cplx* EsT = Ft + (size_t)JB*n2*MtP;
  cplx* Es  = EsT + (size_t)n2*dh;
  int nj = n2/JB;
  int ci = blockIdx.x / nj, jg = blockIdx.x % nj;
  int tid = threadIdx.x, bd = blockDim.x;
  float mu = 0.f, inv = 1.f, ga = 1.f, be = 0.f;
  float bmu = 0.f, binv = 1.f, bga_ = 1.f, bbe_ = 0.f;
  if(st){
    int c = ci % Cch, n = ci / Cch;
    float2 sv = st[n*(Cch/cpg) + c/cpg];
    mu = sv.x; inv = sv.y; ga = gam[c]; be = bet[c];
  }
  if(f2){
    int c = ci % Cch;
    float2 bv = bst[c];
    bmu = bv.x; binv = bv.y; bga_ = bga[c]; bbe_ = bbe[c];
  }
  const float* fbase = f + ((size_t)ci*n2 + (size_t)jg*JB)*n2*n2;
  const float* f2base = f2 ? (f2 + ((size_t)ci*n2 + (size_t)jg*JB)*n2*n2) : nullptr;
  for(int t = tid; t < JB*n2*n2; t += bd){
    int sj = t/(n2*n2); int r = t - sj*n2*n2;
    float v = fbase[(size_t)sj*n2*n2 + r];
    if(st){ v = (v - mu)*inv*ga + be; if(relu) v = fmaxf(v, 0.f); }
    if(f2){
      float vb = (f2base[(size_t)sj*n2*n2 + r] - bmu)*binv*bga_ + bbe_;
      v = fmaxf(v + vb, 0.f);
    }
    ft[sj*n2*fs + (r/n2)*fs + (r%n2)] = v;
  }
  for(int t = tid; t < n2*dh; t += bd){
    int g = t/dh, d = t - g*dh;
    EsT[t] = E[(cwt+d+off)*n2 + g];
  }
  for(int t = tid; t < Mt*n2; t += bd){
    int r = t/n2, a = t - r*n2;
    Es[r*es + a] = E[(r+off)*n2 + a];
  }
  __syncthreads();
  int slab = tid / tpj, tl = tid - slab*tpj;
  {
    int a = tl/hg2, dg = tl - a*hg2;
    int d0 = 2*dg;
    const float* fr = ft + slab*n2*fs + a*fs;
    float ax0=0.f, ax1=0.f, ay0=0.f, ay1=0.f;
    for(int g = 0; g < n2; ++g){
      float v = fr[g];
      const float4* e4 = (const float4*)(EsT + g*dh + d0);
      float4 ea = e4[0];
      ax0 += v*ea.x; ay0 -= v*ea.y;
      ax1 += v*ea.z; ay1 -= v*ea.w;
    }
    cplx* Fp = Ft + slab*n2*MtP + a*MtP;
    float vx[2] = {ax0, ax1};
    float vy[2] = {ay0, ay1};
    #pragma unroll
    for(int u = 0; u < 2; ++u){
      int d = d0+u;
      Fp[cwt+d] = make_float2(vx[u], vy[u]);
      if(d > 0) Fp[cwt-d] = make_float2(vx[u], -vy[u]);
    }
  }
  __syncthreads();
  {
    int ph = tl/ngB, qg = tl - ph*ngB; int q0 = 2*qg;
    int p = cwt + ph;
    float ax0=0.f, ax1=0.f, ay0=0.f, ay1=0.f;
    const cplx* Fb = Ft + slab*n2*MtP;
    for(int a = 0; a < n2; ++a){
      cplx e = Es[p*es + a];
      const float4* F4 = (const float4*)(Fb + a*MtP + q0);
      float4 Fa = F4[0];
      ax0 += e.x*Fa.x + e.y*Fa.y;  ay0 += e.x*Fa.y - e.y*Fa.x;
      ax1 += e.x*Fa.z + e.y*Fa.w;  ay1 += e.x*Fa.w - e.y*Fa.z;
    }
    float invn = 1.0f/((float)n2*(float)n2);
    int j = jg*JB + slab;
    cplx* hp = hf + ((size_t)ci*n2 + j)*Mt*Mt + p*Mt;
    cplx* hpm = hf + ((size_t)ci*n2 + j)*Mt*Mt + (cwt-ph)*Mt;
    float vx[2] = {ax0, ax1};
    float vy[2] = {ay0, ay1};
    #pragma unroll
    for(int u = 0; u < 2; ++u){
      int q = q0+u;
      if(q < Mt){
        if(ph == 0) hp[q] = make_float2(vx[u]*invn, vy[u]*invn);
        else        hpm[Mt-1-q] = make_float2(vx[u]*invn, -vy[u]*invn);
      }
    }
  }
}

// X Hermitian-halved + l-split
template<int LOUT>
__global__ void k_Xstep_h(const cplx* __restrict__ hf, const float* __restrict__ Wst,
                          cplx* __restrict__ X, int b, int Mt, int CI, int Ltot){
  int M = 2*b-1, n2 = 2*b, MM = M*M;
  int off = (M - Mt)/2, cw = (Mt-1)/2;
  int MtMt = Mt*Mt, HH = (MtMt+1)/2;
  int lbase = blockIdx.y*LOUT;
  int total = CI*HH;
  int idx = blockIdx.x*blockDim.x + threadIdx.x;
  if(idx >= total) return;
  int t = idx % HH;
  int ci = idx/HH;
  int p = t / Mt, q = t - p*Mt;
  int pm = Mt-1-p, qm = Mt-1-q;
  bool ism = (t < HH-1);
  float sgn = ((p + q) & 1) ? -1.f : 1.f;
  int dp = iabs_(p-cw), dq = iabs_(q-cw);
  int lmin = dp > dq ? dp : dq;
  float ax[LOUT], ay[LOUT];
  #pragma unroll
  for(int li = 0; li < LOUT; ++li){ ax[li] = 0.f; ay[li] = 0.f; }
  int wpq = (p+off)*M + (q+off);
  const cplx* hp = hf + (size_t)ci*n2*MtMt + (size_t)p*Mt + q;
  for(int j = 0; j < n2; ++j){
    cplx v = hp[(size_t)j*MtMt];
    const float* wj = Wst + ((size_t)j*b + lbase)*MM + wpq;
    #pragma unroll
    for(int li = 0; li < LOUT; ++li){
      if(lbase + li >= lmin){
        float w = wj[(size_t)li*MM];
        ax[li] += w*v.x; ay[li] += w*v.y;
      }
    }
  }
  cplx* xp = X + ((size_t)ci*Ltot + lbase)*MtMt;
  #pragma unroll
  for(int li = 0; li < LOUT; ++li){
    if(lbase + li >= lmin){
      xp[(size_t)li*MtMt + p*Mt + q] = make_float2(ax[li], ay[li]);
      if(ism) xp[(size_t)li*MtMt + pm*Mt + qm] = make_float2(sgn*ax[li], -sgn*ay[li]);
    }else{
      xp[(size_t)li*MtMt + p*Mt + q] = make_float2(0.f, 0.f);
      if(ism) xp[(size_t)li*MtMt + pm*Mt + qm] = make_float2(0.f, 0.f);
    }
  }
}

__global__ void k_what(const float* __restrict__ w, cplx* __restrict__ what,
                       const cplx* __restrict__ E, int n2, int Mt, int off, int OI){
  int total = OI*2*Mt;
  int idx = blockIdx.x*blockDim.x + threadIdx.x;
  if(idx >= total) return;
  int p = idx % Mt;
  int bi = (idx/Mt) & 1;
  int oi = idx/(2*Mt);
  const float* wr = w + (size_t)oi*4*n2 + (size_t)bi*2*n2;
  float sr = 0.f, si = 0.f;
  for(int a = 0; a < n2; ++a){
    float v = wr[2*a] + wr[2*a+1];
    cplx e = E[(p+off)*n2 + a];
    sr += v*e.x; si -= v*e.y;
  }
  what[idx] = make_float2(sr, si);
}

// ---- ystep: Hermitian-halved (pp,qq) grid, both bi in one thread ----
// zstep reads only rows pp <= l, so mirror-write only the center row (pp == l).
__global__ void k_ystep_h(const cplx* __restrict__ X, const float* __restrict__ Dg,
                          cplx* __restrict__ Y, int CI, int Wt, int Wd, int Lx, int Ld){
  int l = blockIdx.z;
  int K21 = 2*l+1;
  int KK = K21*K21, HH = (KK+1)/2;
  int cw = (Wt-1)/2, cwd = (Wd-1)/2;
  int l0 = cw - l, l0d = cwd - l;
  int tot = CI*HH;
  int idx = blockIdx.x*blockDim.x + threadIdx.x;
  if(idx >= tot) return;
  int t = idx % HH;
  int ci = idx/HH;
  int pp = t/K21, qq = t - pp*K21;
  int ppm = K21-1-pp, qqm = K21-1-qq;
  bool ism = (t < HH-1) && (pp == l);
  float sgn = ((pp + qq) & 1) ? -1.f : 1.f;
  const cplx* xp = X + (((size_t)ci*Lx + l)*Wt + (pp+l0))*Wt + l0;
  const float* dp0 = Dg + (((size_t)0*Ld + l)*Wd + (qq+l0d))*Wd + l0d;
  const float* dp1 = Dg + (((size_t)1*Ld + l)*Wd + (qq+l0d))*Wd + l0d;
  float s0x=0.f, s0y=0.f, s1x=0.f, s1y=0.f;
  for(int k = 0; k < K21; ++k){
    cplx v = xp[k];
    float d0 = dp0[k], d1 = dp1[k];
    s0x += d0*v.x; s0y += d0*v.y;
    s1x += d1*v.x; s1y += d1*v.y;
  }
  size_t yoff = (size_t)CI*2*((size_t)l*(2*l-1)*(2*l+1)/3);
  cplx* yb = Y + yoff + (size_t)ci*K21*2*K21;
  yb[(pp*2+0)*K21 + qq] = make_float2(s0x, s0y);
  yb[(pp*2+1)*K21 + qq] = make_float2(s1x, s1y);
  if(ism){
    yb[(ppm*2+0)*K21 + qqm] = make_float2(sgn*s0x, -sgn*s0y);
    yb[(ppm*2+1)*K21 + qqm] = make_float2(sgn*s1x, -sgn*s1y);
  }
}

// Z via 2D (c,o) register tile, Hermitian-halved (p,q) grid with SIGNED conj mirror.
// mir==0 skips mirror stores (consumer reads only the lower half).
template<int NC, int NO>
__global__ void k_zstep2(const cplx* __restrict__ Y, const cplx* __restrict__ what,
                         cplx* __restrict__ Z, int C, int O, int I, int Wt, int mir){
  int l = blockIdx.z;
  int Lz = gridDim.z;
  int K21 = 2*l+1;
  int cw = (Wt-1)/2;
  int l0 = cw - l;
  int WW = Wt*Wt, HH = (WW+1)/2;
  int Cg = C/NC, Og = O/NO;
  int tot = Cg*Og*HH;
  int idx = blockIdx.x*blockDim.x + threadIdx.x;
  if(idx >= tot) return;
  int t = idx % HH;
  int og = (idx/HH) % Og;
  int cg = idx/(HH*Og);
  int p = t / Wt, q = t - p*Wt;
  int pm = Wt-1-p, qm = Wt-1-q;
  bool ism = (t < HH-1) && mir;
  float sgn = ((p + q) & 1) ? -1.f : 1.f;
  int c0 = cg*NC, o0 = og*NO;
  bool valid = (iabs_(p-cw) <= l) && (iabs_(q-cw) <= l);
  if(!valid){
    cplx z0 = make_float2(0.f, 0.f);
    #pragma unroll
    for(int a = 0; a < NC; ++a)
      #pragma unroll
      for(int tt = 0; tt < NO; ++tt){
        size_t base = (((size_t)(c0+a)*O + (o0+tt))*Lz + l)*Wt;
        Z[(base + p)*Wt + q] = z0;
        if(ism) Z[(base + pm)*Wt + qm] = z0;
      }
    return;
  }
  int pp = p - l0, qq = q - l0;
  size_t yoff = (size_t)C*I*2*((size_t)l*(2*l-1)*(2*l+1)/3);
  const cplx* yb = Y + yoff + ((size_t)pp*2)*K21 + qq;
  size_t yci = (size_t)K21*2*K21;
  const cplx* wb = what + q;
  float ax[NC][NO], ay[NC][NO];
  #pragma unroll
  for(int a = 0; a < NC; ++a)
    #pragma unroll
    for(int tt = 0; tt < NO; ++tt){ ax[a][tt] = 0.f; ay[a][tt] = 0.f; }
  for(int i = 0; i < I; ++i){
    cplx y0[NC], y1[NC];
    #pragma unroll
    for(int a = 0; a < NC; ++a){
      const cplx* yp = yb + (size_t)((c0+a)*I + i)*yci;
      y0[a] = yp[0];
      y1[a] = yp[K21];
    }
    #pragma unroll
    for(int tt = 0; tt < NO; ++tt){
      size_t wo = (size_t)(((o0+tt)*I + i)*2)*Wt;
      cplx w0 = wb[wo];
      cplx w1 = wb[wo + Wt];
      #pragma unroll
      for(int a = 0; a < NC; ++a){
        ax[a][tt] += y0[a].x*w0.x + y0[a].y*w0.y + y1[a].x*w1.x + y1[a].y*w1.y;
        ay[a][tt] += y0[a].y*w0.x - y0[a].x*w0.y + y1[a].y*w1.x - y1[a].x*w1.y;
      }
    }
  }
  #pragma unroll
  for(int a = 0; a < NC; ++a)
    #pragma unroll
    for(int tt = 0; tt < NO; ++tt){
      size_t base = (((size_t)(c0+a)*O + (o0+tt))*Lz + l)*Wt;
      Z[(base + p)*Wt + q] = make_float2(ax[a][tt], ay[a][tt]);
      if(ism) Z[(base + pm)*Wt + qm] = make_float2(sgn*ax[a][tt], -sgn*ay[a][tt]);
    }
}

// half!=0: emit only lower-half (p,q) cells (consumer reads t < HH only)
__global__ void k_zid(const cplx* __restrict__ X, const float* __restrict__ w,
                      cplx* __restrict__ Z, int C, int O, int I, int Lz, int Wt, int Wx, int Lx,
                      int half){
  int WW = Wt*Wt;
  int HH = half ? (WW+1)/2 : WW;
  int total = C*O*Lz*HH;
  int idx = blockIdx.x*blockDim.x + threadIdx.x;
  if(idx >= total) return;
  int t = idx % HH;
  int q = t % Wt;
  int p = t / Wt;
  int l = (idx/HH) % Lz;
  int o = (idx/(HH*Lz)) % O;
  int c = idx/(HH*Lz*O);
  int cw = (Wt-1)/2, offx = (Wx-Wt)/2;
  float sx = 0.f, sy = 0.f;
  if(iabs_(p-cw) <= l && iabs_(q-cw) <= l){
    for(int i = 0; i < I; ++i){
      cplx v = X[((((size_t)c*I + i)*Lx + l)*Wx + p + offx)*Wx + q + offx];
      float wv = w[o*I + i];
      sx += wv*v.x; sy += wv*v.y;
    }
  }
  Z[((((size_t)c*O + o)*Lz + l)*Wt + p)*Wt + q] = make_float2(sx, sy);
}

// fused: out[n,c] = sum_jag relu( relu(gn(a)) + bn(b) ) * wq[j] / 64
__global__ void k_integrate2(const float* __restrict__ a, const float* __restrict__ bb,
                             const float2* __restrict__ gst, const float* __restrict__ gga,
                             const float* __restrict__ gbe,
                             const float2* __restrict__ bst, const float* __restrict__ bga,
                             const float* __restrict__ bbe,
                             const double* __restrict__ wq4, float* __restrict__ out,
                             int C, int G){
  int nc = blockIdx.x;
  int n = nc / C, c = nc % C;
  int cpg = C/G;
  float2 gs = gst[n*G + c/cpg];
  float2 bs = bst[c];
  float ga_ = gga[c], ge = gbe[c], ba = bga[c], be = bbe[c];
  const float* ap = a + (size_t)nc*512;
  const float* bp = bb + (size_t)nc*512;
  float s = 0.f;
  for(int t = threadIdx.x; t < 512; t += 64){
    int j = t >> 6;
    float va = fmaxf((ap[t]-gs.x)*gs.y*ga_ + ge, 0.f);
    float vb = (bp[t]-bs.x)*bs.y*ba + be;
    float h = fmaxf(va + vb, 0.f);
    s += h * (float)wq4[j];
  }
  for(int o = 32; o > 0; o >>= 1) s += __shfl_down(s, o);
  if(threadIdx.x == 0) out[nc] = s * (1.f/64.f);
}

// ======================= launch =======================
extern "C" void kernel_launch(void* const* d_in, const int* in_sizes, int n_in,
                              void* d_out, int out_size, void* d_ws, size_t ws_size,
                              hipStream_t stream){
  const float* xin = (const float*)d_in[0];
  const float* w0p = (const float*)d_in[1];
  const float* g0p = (const float*)d_in[2];
  const float* b0p = (const float*)d_in[3];
  const float* w1ap = (const float*)d_in[4];
  const float* g1ap = (const float*)d_in[5];
  const float* b1ap = (const float*)d_in[6];
  const float* w1bp = (const float*)d_in[7];
  const float* g1bp = (const float*)d_in[8];
  const float* b1bp = (const float*)d_in[9];
  const float* w1sp = (const float*)d_in[10];
  const float* g1sp = (const float*)d_in[11];
  const float* b1sp = (const float*)d_in[12];
  const float* w2ap = (const float*)d_in[13];
  const float* g2ap = (const float*)d_in[14];
  const float* b2ap = (const float*)d_in[15];
  const float* w2bp = (const float*)d_in[16];
  const float* g2bp = (const float*)d_in[17];
  const float* b2bp = (const float*)d_in[18];
  const float* w2sp = (const float*)d_in[19];
  const float* g2sp = (const float*)d_in[20];
  const float* b2sp = (const float*)d_in[21];
  float* outp = (float*)d_out;

  char* ws = (char*)d_ws;
  size_t off = 0;
  auto alloc = [&](size_t bytes)->char*{
    char* p = ws + off;
    off = (off + bytes + 255) & ~(size_t)255;
    return p;
  };
  // tables (persistent)
  double* lf   = (double*)alloc(130*8);
  double* wq   = (double*)alloc(120*8);
  cplx* E16    = (cplx*)alloc(31*32*8);
  cplx* E8     = (cplx*)alloc(15*16*8);
  cplx* E4     = (cplx*)alloc(7*8*8);
  cplx* E0f    = (cplx*)alloc(31*64*8);
  float* d032w = (float*)alloc((size_t)64*16*31*4);
  float* dg32  = (float*)alloc((size_t)2*16*31*4);
  float* Wi16  = (float*)alloc((size_t)32*16*961*4);
  float* Wx16  = (float*)alloc((size_t)32*16*961*4);
  float* Dg16  = (float*)alloc((size_t)2*16*961*4);
  float* Wi8   = (float*)alloc((size_t)16*8*225*4);
  float* Wx8   = (float*)alloc((size_t)16*8*225*4);
  float* Dg8   = (float*)alloc((size_t)2*8*225*4);
  float* Wi4   = (float*)alloc((size_t)8*4*49*4);
  // K tables
  float* K16   = (float*)alloc((size_t)8*16*225*4);
  float* KB16  = (float*)alloc((size_t)8*16*225*4);
  float* K8    = (float*)alloc((size_t)4*8*49*4);
  float* KB8   = (float*)alloc((size_t)4*8*49*4);
  float* WxDC16= (float*)alloc(8*4);
  float* WxDC8 = (float*)alloc(4*4);
  // stat partials
  float2* part_f = (float2*)alloc(8192*8);
  float2* st_h0 = (float2*)alloc(256*8);
  float2* st_l1 = (float2*)alloc(256*8);
  float2* st_l2 = (float2*)alloc(256*8);
  float2* st_s1 = (float2*)alloc(256*8);
  float2* st_l3 = (float2*)alloc(256*8);
  float2* st_l4 = (float2*)alloc(256*8);
  float2* st_s2 = (float2*)alloc(256*8);
  // arenas
  char* A_ZHF = alloc((size_t)63*1024*1024);
  char* A_X   = alloc((size_t)32*1024*1024);
  char* A_H1  = alloc((size_t)34*1024*1024);
  char* A_H2  = alloc((size_t)34*1024*1024);
  char* A_S   = alloc((size_t)8*1024*1024);

  // phase aliases
  cplx* xf0    = (cplx*)(A_S);
  cplx* X0     = (cplx*)(A_S + (512<<10));
  cplx* what0  = (cplx*)(A_S + (768<<10));
  cplx* Psi0   = (cplx*)(A_S + (1<<20));
  cplx* Zt0    = (cplx*)A_ZHF;
  float* h0    = (float*)A_H1;
  cplx* hf1    = (cplx*)A_ZHF;
  cplx* X1     = (cplx*)A_X;
  cplx* what1a = (cplx*)A_S;
  cplx* Y1a    = (cplx*)A_H2;
  cplx* Z1a    = (cplx*)A_ZHF;
  cplx* X1b    = (cplx*)A_S;
  cplx* what1b = (cplx*)(A_S + (4<<20));
  cplx* Y1b    = (cplx*)A_H1;
  cplx* Z1b    = (cplx*)A_ZHF;
  float* left2 = (float*)A_H1;
  cplx* Z1s    = (cplx*)A_ZHF;
  float* sc1   = (float*)(A_H1 + (12<<20));
  cplx* hf2    = (cplx*)A_ZHF;
  cplx* X2     = (cplx*)A_X;
  cplx* what2a = (cplx*)A_S;
  cplx* Y2a    = (cplx*)A_H2;
  cplx* Z2a    = (cplx*)A_ZHF;
  cplx* X2b    = (cplx*)A_S;
  cplx* what2b = (cplx*)(A_S + (1<<20));
  cplx* Y2b    = (cplx*)(A_S + (2<<20));
  cplx* Z2b    = (cplx*)A_ZHF;
  float* left4 = (float*)A_H1;
  cplx* Z2s    = (cplx*)A_ZHF;
  float* sc2   = (float*)(A_H1 + (4<<20));

  auto ifftb2_smem = [](int b, int JB)->size_t{
    int M = 2*b-1, n2 = 2*b;
    return (size_t)(M*n2 + JB*M*n2)*8;
  };
  auto fft2b_smem = [](int b, int Mt, int JB)->size_t{
    int n2 = 2*b; int ng = (Mt+3)/4, MtP = 4*ng;
    int dh = (Mt+1)/2;
    return (size_t)(JB*n2*(n2+1))*4 + (size_t)(JB*n2*MtP)*8
         + (size_t)(n2*dh)*8 + (size_t)(Mt*(n2+1))*8;
  };

  // ---- tables ----
  k_tables<<<1,256,0,stream>>>(lf, wq);
  k_twiddle<<<(31*32+255)/256,256,0,stream>>>(E16, 31, 32, 15,  1.0);
  k_twiddle<<<1,256,0,stream>>>(E8, 15, 16, 7,  1.0);
  k_twiddle<<<1,64,0,stream>>>(E4, 7, 8, 3,  1.0);
  k_twiddle<<<(31*64+255)/256,256,0,stream>>>(E0f, 31, 64, 15, -1.0);
  k_wigner_col0<<<(64*16*31+255)/256,256,0,stream>>>(lf, d032w, 64, 16, 31, 0, 32, wq, 2);
  k_wigner_col0<<<(2*16*31+255)/256,256,0,stream>>>(lf, dg32, 2, 16, 31, 1, 0, wq, 0);
  k_wigner_full2<<<(32*16*961+255)/256,256,0,stream>>>(lf, Wi16, Wx16, 32, 16, 31, 16, wq+64);
  k_wigner_full<<<(2*16*961+255)/256,256,0,stream>>>(lf, Dg16, 2, 16, 31, 1, 0, wq, 0, 0);
  k_wigner_full2<<<(16*8*225+255)/256,256,0,stream>>>(lf, Wi8, Wx8, 16, 8, 15, 8, wq+96);
  k_wigner_full<<<(2*8*225+255)/256,256,0,stream>>>(lf, Dg8, 2, 8, 15, 1, 0, wq, 0, 0);
  k_wigner_full<<<(8*4*49+255)/256,256,0,stream>>>(lf, Wi4, 8, 4, 7, 0, 4, wq, 1, 1);
  k_ktab<<<(8*16*225+255)/256,256,0,stream>>>(Wx16, Wi16, K16, KB16, 8, 16, 16, 15, 31, 8, 32);
  k_ktab<<<(4*8*49+255)/256,256,0,stream>>>(Wx8, Wi8, K8, KB8, 4, 8, 8, 7, 15, 4, 16);
  k_wxdc<<<1,64,0,stream>>>(Wx16, WxDC16, 8, 16, 31, 32);
  k_wxdc<<<1,64,0,stream>>>(Wx8, WxDC8, 4, 8, 15, 16);

  // ---- layer 0: s2_conv(x, w0, 32, 16); GN stats fused into ifft ----
  k_fft0<<<(1536*31+255)/256,256,0,stream>>>(xin, xf0, E0f);
  k_what0<<<(96*2*31+255)/256,256,0,stream>>>(w0p, E0f, what0);
  k_X0<<<(24*16*31+255)/256,256,0,stream>>>(xf0, d032w, X0);
  k_Psi0<<<(96*16*31+255)/256,256,0,stream>>>(what0, dg32, Psi0);
  k_Z0<<<(8*32*16*961+255)/256,256,0,stream>>>(X0, Psi0, Zt0);
  k_ifft_b2<4,1><<<8*32*8,512,ifftb2_smem(16,4),stream>>>(Zt0, Wi16, E16, h0, part_f, 16);
  k_gstat_fin<<<1,128,0,stream>>>(part_f, st_h0, 8, 32, 16, 8, 1.f/64.f);

  // ---- layer 1a: so3_conv(h, w1a, 16, 16) ----
  k_fft2_b<<<256*16,512,fft2b_smem(16,31,2),stream>>>(h0, hf1, E16, 16, 31, 2,
      st_h0, g0p, b0p, 32, 2, 1, nullptr, nullptr, nullptr, nullptr);
  { dim3 g((256*481+255)/256, 2);
    k_Xstep_h<8><<<g,256,0,stream>>>(hf1, Wx16, X1, 16, 31, 256, 16); }
  k_what<<<(1024*2*31+255)/256,256,0,stream>>>(w1ap, what1a, E16, 32, 31, 0, 1024);
  { dim3 g((256*481+255)/256,1,16);
    k_ystep_h<<<g,256,0,stream>>>(X1, Dg16, Y1a, 256, 31, 31, 16, 16); }
  { dim3 g((2*8*481+255)/256,1,16);
    k_zstep2<4,4><<<g,256,0,stream>>>(Y1a, what1a, Z1a, 8, 32, 32, 31, 1); }
  k_gstat<8><<<256*4,256,0,stream>>>(Z1a, Wi16, part_f, 16);
  k_gstat_fin<<<1,128,0,stream>>>(part_f, st_l1, 8, 32, 16, 4, 1.f/64.f);
  k_xk<<<(256*120+255)/256,256,0,stream>>>(Z1a, K16, KB16, WxDC16,
                                           st_l1, g1ap, b1ap, X1b,
                                           256, 32, 16, 8, 16, 15, 31, 8);

  // ---- layer 1b: so3_conv(left, w1b, 16, 8); GN stats fused into ifft ----
  k_what<<<(2048*2*15+255)/256,256,0,stream>>>(w1bp, what1b, E16, 32, 15, 8, 2048);
  { dim3 g((256*113+255)/256,1,8);
    k_ystep_h<<<g,256,0,stream>>>(X1b, Dg16, Y1b, 256, 15, 31, 8, 16); }
  { dim3 g((4*16*113+255)/256,1,8);
    k_zstep2<2,4><<<g,256,0,stream>>>(Y1b, what1b, Z1b, 8, 64, 32, 15, 0); }
  k_ifft_b2<16,1><<<8*64,512,ifftb2_smem(8,16),stream>>>(Z1b, Wi8, E8, left2, part_f, 8);
  k_gstat_fin<<<1,128,0,stream>>>(part_f, st_l2, 8, 64, 16, 1, 1.f/64.f);

  // ---- layer 1s: shortcut conv; BN stats fused into ifft ----
  k_zid<<<(8*64*8*113+255)/256,256,0,stream>>>(X1, w1sp, Z1s, 8, 64, 32, 8, 15, 31, 16, 1);
  k_ifft_b2<16,1><<<8*64,512,ifftb2_smem(8,16),stream>>>(Z1s, Wi8, E8, sc1, part_f, 8);
  k_gstat_finB<<<1,128,0,stream>>>(part_f, st_s1, 8, 64, 1, 1.f/128.f);

  // ---- layer 2a: so3_conv(h, w2a, 8, 8); residual join fused into fft2 staging ----
  k_fft2_b<<<512*4,256,fft2b_smem(8,15,4),stream>>>(left2, hf2, E8, 8, 15, 4,
      st_l2, g1bp, b1bp, 64, 4, 1, sc1, st_s1, g1sp, b1sp);
  { dim3 g((512*113+255)/256, 2);
    k_Xstep_h<4><<<g,256,0,stream>>>(hf2, Wx8, X2, 8, 15, 512, 8); }
  k_what<<<(4096*2*15+255)/256,256,0,stream>>>(w2ap, what2a, E8, 16, 15, 0, 4096);
  { dim3 g((512*113+255)/256,1,8);
    k_ystep_h<<<g,256,0,stream>>>(X2, Dg8, Y2a, 512, 15, 15, 8, 8); }
  { dim3 g((4*16*113+255)/256,1,8);
    k_zstep2<2,4><<<g,256,0,stream>>>(Y2a, what2a, Z2a, 8, 64, 64, 15, 1); }
  k_gstat<16><<<512,256,0,stream>>>(Z2a, Wi8, part_f, 8);
  k_gstat_fin<<<1,128,0,stream>>>(part_f, st_l3, 8, 64, 16, 1, 1.f/64.f);
  k_xk<<<(512*28+255)/256,256,0,stream>>>(Z2a, K8, KB8, WxDC8,
                                          st_l3, g2ap, b2ap, X2b,
                                          512, 64, 16, 4, 8, 7, 15, 4);

  // ---- layer 2b: so3_conv(left, w2b, 8, 4); GN stats fused into ifft ----
  k_what<<<(8192*2*7+255)/256,256,0,stream>>>(w2bp, what2b, E8, 16, 7, 4, 8192);
  { dim3 g((512*25+255)/256,1,4);
    k_ystep_h<<<g,256,0,stream>>>(X2b, Dg8, Y2b, 512, 7, 15, 4, 8); }
  { dim3 g((8*64*25+255)/256,1,4);
    k_zstep2<1,2><<<g,256,0,stream>>>(Y2b, what2b, Z2b, 8, 128, 64, 7, 1); }
  k_ifft_s<<<8*128*8,64,(49+56)*8,stream>>>(Z2b, Wi4, E4, left4, part_f, 1, 4);
  k_gstat_fin<<<1,256,0,stream>>>(part_f, st_l4, 8, 128, 32, 8, 1.f/32.f);

  // ---- layer 2s: shortcut conv; BN stats fused into ifft ----
  k_zid<<<(8*128*4*49+255)/256,256,0,stream>>>(X2, w2sp, Z2s, 8, 128, 64, 4, 7, 15, 8, 0);
  k_ifft_s<<<8*128*8,64,(49+56)*8,stream>>>(Z2s, Wi4, E4, sc2, part_f, 1, 4);
  k_gstat_finB<<<1,128,0,stream>>>(part_f, st_s2, 8, 128, 8, 1.f/64.f);

  // ---- fused residual join + integrate ----
  k_integrate2<<<1024,64,0,stream>>>(left4, sc2, st_l4, g2bp, b2bp,
                                     st_s2, g2sp, b2sp, wq+112, outp, 128, 32);
}